// Round 8
// baseline (1149.382 us; speedup 1.0000x reference)
//
#include <hip/hip_runtime.h>
#include <hip/hip_cooperative_groups.h>

namespace cg = cooperative_groups;

#define BIGF 1e20f
#define VF   1e10f

constexpr float SQ2 = 1.41421356237309515f;  // fp32 0x3FB504F3, == jnp.sqrt(2.0) in f32

// ---------------------------------------------------------------------------
// DPP helpers
// ---------------------------------------------------------------------------
__device__ __forceinline__ float dpp_left(float x)
{
    int o = __builtin_amdgcn_update_dpp(0x60AD78ECu /*1e20f*/, __float_as_int(x),
                                        0x138, 0xF, 0xF, false);   // WAVE_SHR1
    return __int_as_float(o);
}
__device__ __forceinline__ float dpp_right(float x)
{
    int o = __builtin_amdgcn_update_dpp(0x60AD78ECu /*1e20f*/, __float_as_int(x),
                                        0x130, 0xF, 0xF, false);   // WAVE_SHL1
    return __int_as_float(o);
}
template<int CTRL>
__device__ __forceinline__ float qdpp(float x)   // quad_perm xor patterns
{
    return __int_as_float(__builtin_amdgcn_update_dpp(0, __float_as_int(x),
                                                      CTRL, 0xF, 0xF, true));
}
__device__ __forceinline__ float fmed3(float a, float b, float c)
{
    return __builtin_amdgcn_fmed3f(a, b, c);
}

__device__ __forceinline__ void load_row8(const float* __restrict__ M, int r, int c0, float v[8])
{
    const float4* q = (const float4*)(M + ((long)r << 9) + c0);
    float4 a = q[0], b = q[1];
    v[0] = a.x; v[1] = a.y; v[2] = a.z; v[3] = a.w;
    v[4] = b.x; v[5] = b.y; v[6] = b.z; v[7] = b.w;
}

// 3pt chamfer step: nv <- min(cur, p+1, min(neighbors)+SQ2)
__device__ __forceinline__ void step8(const float cur[8], const float p[8], float nv[8])
{
    float left  = dpp_left(p[7]);
    float right = dpp_right(p[0]);
    #pragma unroll
    for (int j = 0; j < 8; ++j) {
        float l  = (j == 0) ? left  : p[j - 1];
        float rr = (j == 7) ? right : p[j + 1];
        nv[j] = fminf(fminf(cur[j], p[j] + 1.0f), fminf(l, rr) + SQ2);
    }
}

// LDS stash helpers (slot = 512-float row slot, lane-contiguous 8 cols @ c0)
__device__ __forceinline__ void sst_(float* st, int slot, int c0, const float v[8])
{
    float4* q = (float4*)(st + slot * 512 + c0);
    q[0] = make_float4(v[0], v[1], v[2], v[3]);
    q[1] = make_float4(v[4], v[5], v[6], v[7]);
}
__device__ __forceinline__ void sld_(const float* st, int slot, int c0, float v[8])
{
    const float4* q = (const float4*)(st + slot * 512 + c0);
    float4 a = q[0], b = q[1];
    v[0]=a.x; v[1]=a.y; v[2]=a.z; v[3]=a.w;
    v[4]=b.x; v[5]=b.y; v[6]=b.z; v[7]=b.w;
}

// cone weight, EXACT replica of k_comb's wgt[] formula (compile-time folded)
__device__ constexpr float coneWf(int t)
{
    int ad = (t < 32) ? (32 - t) : (t - 32);
    return (float)ad * 1.41421356237309515f + (float)(32 - ad);
}

// prev <- min(bw, cone32(prev)). 8 cols/lane, scratch = 512-float LDS row.
// Verified bit-exact vs k_comb in R2 (absmax 0.0). Single-wave, no barrier.
__device__ __forceinline__ void cone32_step(float prev[8], const float bw[8],
                                            float* scratch, int L)
{
    int c0 = L << 3;
    *(float4*)(scratch + c0)     = make_float4(prev[0], prev[1], prev[2], prev[3]);
    *(float4*)(scratch + c0 + 4) = make_float4(prev[4], prev[5], prev[6], prev[7]);
    float o[8];
    #pragma unroll
    for (int j = 0; j < 8; ++j) o[j] = bw[j];
    #pragma unroll
    for (int k = 0; k < 9; ++k) {
        int blk = L - 4 + k;
        bool ok = (blk >= 0) && (blk < 64);
        int off = (ok ? blk : 0) << 3;
        float4 x0 = *(const float4*)(scratch + off);
        float4 x1 = *(const float4*)(scratch + off + 4);
        float wv[8] = {x0.x, x0.y, x0.z, x0.w, x1.x, x1.y, x1.z, x1.w};
        #pragma unroll
        for (int e = 0; e < 8; ++e) {
            float val = ok ? wv[e] : BIGF;
            #pragma unroll
            for (int j = 0; j < 8; ++j) {
                const int t = (k - 4) * 8 + e - j + 32;
                if (t >= 0 && t <= 64)
                    o[j] = fminf(o[j], val + coneWf(t));
            }
        }
    }
    #pragma unroll
    for (int j = 0; j < 8; ++j) prev[j] = o[j];
}

// transposed 16-row flush from stash slots. PERM=0: tile h at slot 15+h
// (up rows 16..31). PERM=1: tile h at slot (h+15)&15 (row 0 at slot 15).
// Verified in R2.
template<int PERM>
__device__ __forceinline__ void half_out2(const float* st, float* __restrict__ Xo,
                                          int a2, int L)
{
    int g = L >> 2, j = (L & 3) << 2;
    #pragma unroll
    for (int it = 0; it < 32; ++it) {
        int c = (it << 4) + g;
        float v[4];
        #pragma unroll
        for (int kk = 0; kk < 4; ++kk) {
            int h = j + kk;
            int slot = PERM ? ((h + 15) & 15) : (15 + h);
            v[kk] = st[slot * 512 + c];
        }
        *(float4*)(Xo + (long)c * 512 + a2 + j) = make_float4(v[0], v[1], v[2], v[3]);
    }
}

// ---------------------------------------------------------------------------
// K1: binarize + channel max + dist init + scalar inits
// ---------------------------------------------------------------------------
__global__ __launch_bounds__(256) void k_init(const float* __restrict__ pred,
                                              const float* __restrict__ tgt,
                                              float* __restrict__ bufA,
                                              float* __restrict__ acc,
                                              unsigned* __restrict__ count,
                                              float* __restrict__ minmax)
{
    if (blockIdx.x == 0 && threadIdx.x == 0) { *acc = 0.0f; *count = 0u; }
    if (blockIdx.x == 0 && threadIdx.x < 64)
        minmax[threadIdx.x] = (threadIdx.x & 1) ? 0.0f : BIGF;

    int r = blockIdx.x & 7;
    int k = blockIdx.x >> 3;
    int b = r + 8 * (k >> 10);
    int pix = (k & 1023) * 256 + threadIdx.x;
    long base = (long)b * 3 * 262144 + pix;

    float p0 = pred[base], p1 = pred[base + 262144], p2 = pred[base + 2 * 262144];
    bool fgP = ((p0 + 1.0f) * 0.5f >= 0.7f) ||
               ((p1 + 1.0f) * 0.5f >= 0.7f) ||
               ((p2 + 1.0f) * 0.5f >= 0.7f);

    float t0 = tgt[base], t1 = tgt[base + 262144], t2 = tgt[base + 2 * 262144];
    float mt = fmaxf(fmaxf(t0, t1), t2);

    bufA[(long)b * 262144 + pix]        = fgP ? 0.0f : VF;
    bufA[(long)(16 + b) * 262144 + pix] = VF * (1.0f - mt);
}

// ---------------------------------------------------------------------------
// K_pass: ONE cooperative kernel per (down+up) pass, Y eliminated (down rows
// live in LDS across grid.sync). 512 WGs x 64, 64KB LDS => exactly 2 WGs/CU.
// Structure (math identical to R2's verified k_pass; sync via grid.sync):
//   P0  unseeded band down (stash X rows w>0 / down rows w==0), publish bnd1
//   sync
//   [w>0] local scan1 over bnd1[0..w-1] (redundant per-WG), P1 seeded re-down
//         from LDS X rows (in place)
//   P2  fused band-local up1, publish bnd2
//   sync
//   [w<15] local scan2 over bnd2[15..w+1]
//   P3  final up from stash + transposed write + minmax
// ---------------------------------------------------------------------------
__global__ __launch_bounds__(64) void k_pass(const float* __restrict__ Xin0,
                                             float* __restrict__ Xout0,
                                             float* __restrict__ bnd1,
                                             float* __restrict__ bnd2,
                                             float* __restrict__ minmax,
                                             int final_pass)
{
    cg::grid_group grid = cg::this_grid();
    __shared__ __align__(16) float stash[31 * 512 + 512];   // 65536 B exactly
    float* scratch = stash + 31 * 512;

    int bi = blockIdx.x, m = bi >> 4, w = bi & 15;
    const float* X = Xin0 + ((long)m << 18);
    float* Xo = Xout0 + ((long)m << 18);
    const int L = threadIdx.x;
    int c0 = L << 3, a = w << 5;
    float* b1 = bnd1 + (m << 13);
    float* b2 = bnd2 + (m << 13);

    float p[8], row0[8], buf[8][8];

    // ---------------- P0: unseeded band-local down sweep ----------------
    load_row8(X, a, c0, p);
    #pragma unroll
    for (int j = 0; j < 8; ++j) row0[j] = p[j];          // X row a (== down row 0 unseeded)
    #pragma unroll
    for (int k = 1; k <= 7; ++k) {
        load_row8(X, a + k, c0, buf[k & 7]);
        if (w) sst_(stash, k - 1, c0, buf[k & 7]);       // stash X rows 1..31
    }
    #pragma unroll
    for (int i = 1; i < 32; ++i) {
        if (i + 7 < 32) {
            load_row8(X, a + i + 7, c0, buf[(i + 7) & 7]);
            if (w) sst_(stash, i + 6, c0, buf[(i + 7) & 7]);
        }
        float nv[8]; step8(buf[i & 7], p, nv);
        if (!w) sst_(stash, i - 1, c0, nv);              // w==0: stash down rows
        #pragma unroll
        for (int j = 0; j < 8; ++j) p[j] = nv[j];
    }
    *(float4*)(b1 + (w << 9) + c0)     = make_float4(p[0], p[1], p[2], p[3]);
    *(float4*)(b1 + (w << 9) + c0 + 4) = make_float4(p[4], p[5], p[6], p[7]);
    __threadfence();
    grid.sync();
    __threadfence();

    // ------- local scan1 + P1: seeded down from LDS X rows (w>0) -------
    if (w) {
        float prev[8];
        {
            const float4* s = (const float4*)(b1 + c0);
            float4 s0 = s[0], s1 = s[1];
            prev[0]=s0.x; prev[1]=s0.y; prev[2]=s0.z; prev[3]=s0.w;
            prev[4]=s1.x; prev[5]=s1.y; prev[6]=s1.z; prev[7]=s1.w;
        }
        #pragma unroll 1
        for (int wp = 1; wp < w; ++wp) {
            float bw[8];
            const float4* s = (const float4*)(b1 + (wp << 9) + c0);
            float4 s0 = s[0], s1 = s[1];
            bw[0]=s0.x; bw[1]=s0.y; bw[2]=s0.z; bw[3]=s0.w;
            bw[4]=s1.x; bw[5]=s1.y; bw[6]=s1.z; bw[7]=s1.w;
            cone32_step(prev, bw, scratch, L);
        }
        // seeded down: row a from regs (X row), rows a+1..a+31 from stash
        {
            float nv[8]; step8(row0, prev, nv);
            #pragma unroll
            for (int j = 0; j < 8; ++j) { row0[j] = nv[j]; p[j] = nv[j]; }
        }
        #pragma unroll 1
        for (int i = 1; i < 32; ++i) {
            float cu[8]; sld_(stash, i - 1, c0, cu);     // X row a+i
            float nv[8]; step8(cu, p, nv);
            sst_(stash, i - 1, c0, nv);                  // down row a+i (in place)
            #pragma unroll
            for (int j = 0; j < 8; ++j) p[j] = nv[j];
        }
    }

    // ---------------- P2: fused band-local up1 ----------------
    float q[8];
    #pragma unroll
    for (int j = 0; j < 8; ++j) q[j] = p[j];
    #pragma unroll 1
    for (int i = 1; i < 32; ++i) {
        float cu[8];
        if (i < 31) sld_(stash, 30 - i, c0, cu);         // down row 31-i
        else {
            #pragma unroll
            for (int j = 0; j < 8; ++j) cu[j] = row0[j]; // down row 0
        }
        float nv[8]; step8(cu, q, nv);
        #pragma unroll
        for (int j = 0; j < 8; ++j) q[j] = nv[j];
    }
    *(float4*)(b2 + (w << 9) + c0)     = make_float4(q[0], q[1], q[2], q[3]);
    *(float4*)(b2 + (w << 9) + c0 + 4) = make_float4(q[4], q[5], q[6], q[7]);
    __threadfence();
    grid.sync();
    __threadfence();

    // ------- local scan2 + P3: final up from stash, transposed out -------
    float s2[8];
    if (w == 15) {
        #pragma unroll
        for (int j = 0; j < 8; ++j) s2[j] = BIGF;        // step8 with BIG seed == identity
    } else {
        {
            const float4* s = (const float4*)(b2 + (15 << 9) + c0);
            float4 s0 = s[0], s1 = s[1];
            s2[0]=s0.x; s2[1]=s0.y; s2[2]=s0.z; s2[3]=s0.w;
            s2[4]=s1.x; s2[5]=s1.y; s2[6]=s1.z; s2[7]=s1.w;
        }
        #pragma unroll 1
        for (int wp = 14; wp > w; --wp) {
            float bw[8];
            const float4* s = (const float4*)(b2 + (wp << 9) + c0);
            float4 s0 = s[0], s1 = s[1];
            bw[0]=s0.x; bw[1]=s0.y; bw[2]=s0.z; bw[3]=s0.w;
            bw[4]=s1.x; bw[5]=s1.y; bw[6]=s1.z; bw[7]=s1.w;
            cone32_step(s2, bw, scratch, L);
        }
    }
    float mn = BIGF, mx = -BIGF;
    #pragma unroll 1
    for (int i = 0; i < 16; ++i) {                       // up rows 31..16 (in place)
        float cu[8]; sld_(stash, 30 - i, c0, cu);        // down row 31-i
        float nv[8]; step8(cu, s2, nv);
        sst_(stash, 30 - i, c0, nv);
        #pragma unroll
        for (int j = 0; j < 8; ++j) { s2[j] = nv[j]; mn = fminf(mn, nv[j]); mx = fmaxf(mx, nv[j]); }
    }
    half_out2<0>(stash, Xo, a + 16, L);                  // rows 16..31 at slots 15..30
    #pragma unroll 1
    for (int i = 16; i < 32; ++i) {                      // up rows 15..0
        float cu[8];
        if (i < 31) sld_(stash, 30 - i, c0, cu);
        else {
            #pragma unroll
            for (int j = 0; j < 8; ++j) cu[j] = row0[j]; // down row 0
        }
        float nv[8]; step8(cu, s2, nv);
        sst_(stash, (i < 31) ? (30 - i) : 15, c0, nv);   // row 0 -> dead slot 15
        #pragma unroll
        for (int j = 0; j < 8; ++j) { s2[j] = nv[j]; mn = fminf(mn, nv[j]); mx = fmaxf(mx, nv[j]); }
    }
    half_out2<1>(stash, Xo, a, L);                       // rows 0..15 (perm slot map)

    if (final_pass) {
        for (int o = 32; o > 0; o >>= 1) {
            mn = fminf(mn, __shfl_down(mn, o));
            mx = fmaxf(mx, __shfl_down(mx, o));
        }
        if (L == 0) {
            atomicMin((int*)(minmax + 2 * m),     __float_as_int(mn));
            atomicMax((int*)(minmax + 2 * m + 1), __float_as_int(mx));
        }
    }
}

// ---------------------------------------------------------------------------
// K_loss: NORMALIZED bitonic sort (all comparators min-low) with med3 trick.
// lstage LDS slots XOR-half-swizzled (verified: conflicts 2.36M -> 786K).
// ---------------------------------------------------------------------------
__device__ __forceinline__ void cex(float& lo, float& hi)
{
    float l = fminf(lo, hi);
    hi = fmaxf(lo, hi);
    lo = l;
}
__device__ __forceinline__ void merge8asc(float v[8])
{
    cex(v[0],v[4]); cex(v[1],v[5]); cex(v[2],v[6]); cex(v[3],v[7]);
    cex(v[0],v[2]); cex(v[1],v[3]); cex(v[4],v[6]); cex(v[5],v[7]);
    cex(v[0],v[1]); cex(v[2],v[3]); cex(v[4],v[5]); cex(v[6],v[7]);
}
__device__ __forceinline__ void sort8asc(float v[8])
{
    cex(v[0],v[1]); cex(v[2],v[3]); cex(v[4],v[5]); cex(v[6],v[7]);   // k=2
    cex(v[0],v[3]); cex(v[1],v[2]); cex(v[4],v[7]); cex(v[5],v[6]);   // k=4 rev
    cex(v[0],v[1]); cex(v[2],v[3]); cex(v[4],v[5]); cex(v[6],v[7]);   // k=4 j=1
    cex(v[0],v[7]); cex(v[1],v[6]); cex(v[2],v[5]); cex(v[3],v[4]);   // k=8 rev
    cex(v[0],v[2]); cex(v[1],v[3]); cex(v[4],v[6]); cex(v[5],v[7]);   // j=2
    cex(v[0],v[1]); cex(v[2],v[3]); cex(v[4],v[5]); cex(v[6],v[7]);   // j=1
}
__device__ __forceinline__ void xshfl(float v[8], int j8, float sel)
{
    #pragma unroll
    for (int e = 0; e < 8; ++e) {
        float o = __shfl_xor(v[e], j8);
        v[e] = fmed3(v[e], o, sel);
    }
}
template<int CTRL>
__device__ __forceinline__ void xdpp(float v[8], float sel)
{
    #pragma unroll
    for (int e = 0; e < 8; ++e) {
        float o = qdpp<CTRL>(v[e]);
        v[e] = fmed3(v[e], o, sel);
    }
}
__device__ __forceinline__ void rshfl(float v[8], int tmask, float sel)
{
    float o[8];
    #pragma unroll
    for (int e = 0; e < 8; ++e) o[e] = __shfl_xor(v[7 - e], tmask);
    #pragma unroll
    for (int e = 0; e < 8; ++e) v[e] = fmed3(v[e], o[e], sel);
}
template<int CTRL>
__device__ __forceinline__ void rdpp(float v[8], float sel)
{
    float o[8];
    #pragma unroll
    for (int e = 0; e < 8; ++e) o[e] = qdpp<CTRL>(v[7 - e]);
    #pragma unroll
    for (int e = 0; e < 8; ++e) v[e] = fmed3(v[e], o[e], sel);
}
__device__ __forceinline__ void lstage(float p[8], float q[8], int tmask, float sel, bool rev,
                                       float* sp, float* st, int t)
{
    __syncthreads();
    int sw = (t >> 2) & 1;                 // half-swap swizzle bit
    int o0 = t * 8 + sw * 4;
    int o1 = t * 8 + (sw ^ 1) * 4;
    *(float4*)(sp + o0) = make_float4(p[0], p[1], p[2], p[3]);
    *(float4*)(sp + o1) = make_float4(p[4], p[5], p[6], p[7]);
    *(float4*)(st + o0) = make_float4(q[0], q[1], q[2], q[3]);
    *(float4*)(st + o1) = make_float4(q[4], q[5], q[6], q[7]);
    __syncthreads();
    int pt = t ^ tmask;
    int psw = (pt >> 2) & 1;
    int q0 = pt * 8 + psw * 4;
    int q1 = pt * 8 + (psw ^ 1) * 4;
    float4 a = *(const float4*)(sp + q0), bb = *(const float4*)(sp + q1);
    float4 c = *(const float4*)(st + q0), d = *(const float4*)(st + q1);
    float op[8] = {a.x,a.y,a.z,a.w,bb.x,bb.y,bb.z,bb.w};
    float oq[8] = {c.x,c.y,c.z,c.w,d.x,d.y,d.z,d.w};
    if (rev) {
        #pragma unroll
        for (int e = 0; e < 8; ++e) {
            p[e] = fmed3(p[e], op[7 - e], sel);
            q[e] = fmed3(q[e], oq[7 - e], sel);
        }
    } else {
        #pragma unroll
        for (int e = 0; e < 8; ++e) {
            p[e] = fmed3(p[e], op[e], sel);
            q[e] = fmed3(q[e], oq[e], sel);
        }
    }
}

__global__ __launch_bounds__(512) void k_loss(const float* __restrict__ bufB,
                                              const float* __restrict__ minmax,
                                              float* __restrict__ acc,
                                              unsigned* __restrict__ count,
                                              float* __restrict__ out)
{
    __shared__ float sp[4096];
    __shared__ float st[4096];
    __shared__ float rs[8];

    int t = threadIdx.x;
    int r = blockIdx.x & 7;
    int k = blockIdx.x >> 3;
    int b = r + 8 * (k >> 6);
    int w = k & 63;
    int wi = w >> 3, wj = w & 7;

    int i0 = t << 3;
    int y = wi * 64 + (i0 >> 6);
    int x = wj * 64 + (i0 & 63);

    float mnP = minmax[2 * b],        mxP = minmax[2 * b + 1];
    float mnT = minmax[2 * (16 + b)], mxT = minmax[2 * (16 + b) + 1];
    float sclP = 1.0f / (mxP - mnP + 1e-6f);
    float sclT = 1.0f / (mxT - mnT + 1e-6f);

    float p[8], q[8];
    {
        const float4* P4 = (const float4*)(bufB + (long)b * 262144 + y * 512 + x);
        const float4* T4 = (const float4*)(bufB + (long)(16 + b) * 262144 + y * 512 + x);
        float4 a = P4[0], bb = P4[1], c = T4[0], d = T4[1];
        p[0]=a.x; p[1]=a.y; p[2]=a.z; p[3]=a.w; p[4]=bb.x; p[5]=bb.y; p[6]=bb.z; p[7]=bb.w;
        q[0]=c.x; q[1]=c.y; q[2]=c.z; q[3]=c.w; q[4]=d.x;  q[5]=d.y;  q[6]=d.z;  q[7]=d.w;
        #pragma unroll
        for (int e = 0; e < 8; ++e) {
            p[e] = (p[e] - mnP) * sclP;
            q[e] = (q[e] - mnT) * sclT;
        }
    }

    const float INFP = __builtin_inff();
    sort8asc(p); sort8asc(q);

    #pragma unroll 1
    for (int kk = 16; kk <= 4096; kk <<= 1) {
        int tmask = (kk - 1) >> 3;
        float sel = ((t & (kk >> 4)) == 0) ? -INFP : INFP;
        if (kk == 16)        { rdpp<0xB1>(p, sel); rdpp<0xB1>(q, sel); }
        else if (kk == 32)   { rdpp<0x1B>(p, sel); rdpp<0x1B>(q, sel); }
        else if (tmask < 64) { rshfl(p, tmask, sel); rshfl(q, tmask, sel); }
        else                 lstage(p, q, tmask, sel, true, sp, st, t);

        #pragma unroll 1
        for (int j = kk >> 2; j >= 8; j >>= 1) {
            int j8 = j >> 3;
            float s2 = ((t & j8) == 0) ? -INFP : INFP;
            if (j8 == 1)      { xdpp<0xB1>(p, s2); xdpp<0xB1>(q, s2); }
            else if (j8 == 2) { xdpp<0x4E>(p, s2); xdpp<0x4E>(q, s2); }
            else if (j8 < 64) { xshfl(p, j8, s2); xshfl(q, j8, s2); }
            else              lstage(p, q, j8, s2, false, sp, st, t);
        }
        merge8asc(p); merge8asc(q);
    }

    float s = 0.0f;
    #pragma unroll
    for (int e = 0; e < 8; ++e) { float d = p[e] - q[e]; s += d * d; }
    for (int o = 32; o > 0; o >>= 1) s += __shfl_down(s, o);
    if ((t & 63) == 0) rs[t >> 6] = s;
    __syncthreads();
    if (t == 0) {
        float tot = 0.0f;
        #pragma unroll
        for (int i = 0; i < 8; ++i) tot += rs[i];
        atomicAdd(acc, tot);
        __threadfence();
        unsigned done = atomicAdd(count, 1u);
        if (done == 1023u) {
            float total = atomicAdd(acc, 0.0f);
            float mean = total * (1.0f / 4194304.0f);
            out[0] = mean * 0.005f;
            out[1] = mean;
        }
    }
}

extern "C" void kernel_launch(void* const* d_in, const int* in_sizes, int n_in,
                              void* d_out, int out_size, void* d_ws, size_t ws_size,
                              hipStream_t stream)
{
    const float* pred = (const float*)d_in[0];
    const float* tgt  = (const float*)d_in[1];
    float* out = (float*)d_out;

    char* ws = (char*)d_ws;
    float* bufA     = (float*)ws;                       // 32 MB
    float* bufB     = (float*)(ws + (32ull << 20));     // 32 MB (ping-pong)
    float* Cb       = (float*)(ws + (64ull << 20));     // 1 MB boundary rows (down)
    float* Db       = (float*)(ws + (65ull << 20));     // 1 MB boundary rows (up)
    float* minmax   = (float*)(ws + (66ull << 20));     // 64 floats
    float* acc      = minmax + 64;
    unsigned* count = (unsigned*)(acc + 1);

    k_init<<<16 * 1024, 256, 0, stream>>>(pred, tgt, bufA, acc, count, minmax);

    for (int s = 0; s < 4; ++s) {
        const float* in = (s & 1) ? bufB : bufA;
        float* outb     = (s & 1) ? bufA : bufB;
        int fp = (s == 3) ? 1 : 0;
        void* args[] = { (void*)&in, (void*)&outb, (void*)&Cb, (void*)&Db,
                         (void*)&minmax, (void*)&fp };
        hipLaunchCooperativeKernel(reinterpret_cast<void*>(k_pass),
                                   dim3(512), dim3(64), args, 0, stream);
    }

    k_loss<<<1024, 512, 0, stream>>>(bufA, minmax, acc, count, out);
}

// Round 9
// 428.901 us; speedup vs baseline: 2.6798x; 2.6798x over previous
//
#include <hip/hip_runtime.h>

#define BIGF 1e20f
#define VF   1e10f

constexpr float SQ2 = 1.41421356237309515f;  // fp32 0x3FB504F3, == jnp.sqrt(2.0) in f32

// ---------------------------------------------------------------------------
// DPP helpers
// ---------------------------------------------------------------------------
__device__ __forceinline__ float dpp_left(float x)
{
    int o = __builtin_amdgcn_update_dpp(0x60AD78ECu /*1e20f*/, __float_as_int(x),
                                        0x138, 0xF, 0xF, false);   // WAVE_SHR1
    return __int_as_float(o);
}
__device__ __forceinline__ float dpp_right(float x)
{
    int o = __builtin_amdgcn_update_dpp(0x60AD78ECu /*1e20f*/, __float_as_int(x),
                                        0x130, 0xF, 0xF, false);   // WAVE_SHL1
    return __int_as_float(o);
}
template<int CTRL>
__device__ __forceinline__ float qdpp(float x)   // quad_perm xor patterns
{
    return __int_as_float(__builtin_amdgcn_update_dpp(0, __float_as_int(x),
                                                      CTRL, 0xF, 0xF, true));
}
__device__ __forceinline__ float fmed3(float a, float b, float c)
{
    return __builtin_amdgcn_fmed3f(a, b, c);
}

__device__ __forceinline__ void load_row8(const float* __restrict__ M, int r, int c0, float v[8])
{
    const float4* q = (const float4*)(M + ((long)r << 9) + c0);
    float4 a = q[0], b = q[1];
    v[0] = a.x; v[1] = a.y; v[2] = a.z; v[3] = a.w;
    v[4] = b.x; v[5] = b.y; v[6] = b.z; v[7] = b.w;
}
__device__ __forceinline__ void store_row8(float* __restrict__ M, int r, int c0, const float v[8])
{
    float4* q = (float4*)(M + ((long)r << 9) + c0);
    q[0] = make_float4(v[0], v[1], v[2], v[3]);
    q[1] = make_float4(v[4], v[5], v[6], v[7]);
}

// 3pt chamfer step: nv <- min(cur, p+1, min(neighbors)+SQ2)
__device__ __forceinline__ void step8(const float cur[8], const float p[8], float nv[8])
{
    float left  = dpp_left(p[7]);
    float right = dpp_right(p[0]);
    #pragma unroll
    for (int j = 0; j < 8; ++j) {
        float l  = (j == 0) ? left  : p[j - 1];
        float rr = (j == 7) ? right : p[j + 1];
        nv[j] = fminf(fminf(cur[j], p[j] + 1.0f), fminf(l, rr) + SQ2);
    }
}

// ---------------------------------------------------------------------------
// K1: binarize + channel max + dist init + scalar inits
// ---------------------------------------------------------------------------
__global__ __launch_bounds__(256) void k_init(const float* __restrict__ pred,
                                              const float* __restrict__ tgt,
                                              float* __restrict__ bufA,
                                              float* __restrict__ acc,
                                              unsigned* __restrict__ count,
                                              float* __restrict__ minmax)
{
    if (blockIdx.x == 0 && threadIdx.x == 0) { *acc = 0.0f; *count = 0u; }
    if (blockIdx.x == 0 && threadIdx.x < 64)
        minmax[threadIdx.x] = (threadIdx.x & 1) ? 0.0f : BIGF;

    int r = blockIdx.x & 7;
    int k = blockIdx.x >> 3;
    int b = r + 8 * (k >> 10);
    int pix = (k & 1023) * 256 + threadIdx.x;
    long base = (long)b * 3 * 262144 + pix;

    float p0 = pred[base], p1 = pred[base + 262144], p2 = pred[base + 2 * 262144];
    bool fgP = ((p0 + 1.0f) * 0.5f >= 0.7f) ||
               ((p1 + 1.0f) * 0.5f >= 0.7f) ||
               ((p2 + 1.0f) * 0.5f >= 0.7f);

    float t0 = tgt[base], t1 = tgt[base + 262144], t2 = tgt[base + 2 * 262144];
    float mt = fmaxf(fmaxf(t0, t1), t2);

    bufA[(long)b * 262144 + pix]        = fgP ? 0.0f : VF;
    bufA[(long)(16 + b) * 262144 + pix] = VF * (1.0f - mt);
}

// ---------------------------------------------------------------------------
// K_p1d: phase-1 down. 512 WGs x 64. Ring deepened 8->16 rows (15 in flight
// ~= 1000-1500cy issue cover >= ~900cy HBM latency).
// ---------------------------------------------------------------------------
__global__ __launch_bounds__(64) void k_p1d(const float* __restrict__ X0,
                                            float* __restrict__ Cb)
{
    int bi = blockIdx.x, m = bi >> 4, w = bi & 15;
    const float* X = X0 + ((long)m << 18);
    int c0 = (int)threadIdx.x << 3, a = w << 5;
    float p[8]; load_row8(X, a, c0, p);
    float buf[16][8];
    #pragma unroll
    for (int k = 1; k <= 15; ++k) load_row8(X, a + k, c0, buf[k & 15]);
    #pragma unroll
    for (int i = 1; i < 32; ++i) {
        if (i + 15 < 32) load_row8(X, a + i + 15, c0, buf[(i + 15) & 15]);
        float nv[8]; step8(buf[i & 15], p, nv);
        #pragma unroll
        for (int j = 0; j < 8; ++j) p[j] = nv[j];
    }
    float4* o = (float4*)(Cb + m * 8192 + w * 512 + c0);
    o[0] = make_float4(p[0], p[1], p[2], p[3]);
    o[1] = make_float4(p[4], p[5], p[6], p[7]);
}

// ---------------------------------------------------------------------------
// combine: bwp[wdst] = min(bwp[wdst], cone32(bwp[wsrc]))  (verified exact)
// ---------------------------------------------------------------------------
__device__ __forceinline__ void combine(float* __restrict__ bwp, float* __restrict__ part,
                                        int wdst, int wsrc, int t, int wave, int lane,
                                        const float wreg[8])
{
    const float* bs = bwp + wsrc * 576;
    if (wave <= 8) {
        int base = lane * 8 + 8 * wave;
        float W[16];
        float4 W0 = *(const float4*)(bs + base);
        float4 W1 = *(const float4*)(bs + base + 4);
        W[0]=W0.x; W[1]=W0.y; W[2]=W0.z; W[3]=W0.w;
        W[4]=W1.x; W[5]=W1.y; W[6]=W1.z; W[7]=W1.w;
        float acc[8];
        if (wave < 8) {
            float4 W2 = *(const float4*)(bs + base + 8);
            float4 W3 = *(const float4*)(bs + base + 12);
            W[8]=W2.x; W[9]=W2.y; W[10]=W2.z; W[11]=W2.w;
            W[12]=W3.x; W[13]=W3.y; W[14]=W3.z; W[15]=W3.w;
            #pragma unroll
            for (int j = 0; j < 8; ++j) acc[j] = W[j] + wreg[0];
            #pragma unroll
            for (int dt = 1; dt < 8; ++dt)
                #pragma unroll
                for (int j = 0; j < 8; ++j)
                    acc[j] = fminf(acc[j], W[j + dt] + wreg[dt]);
        } else {
            #pragma unroll
            for (int j = 0; j < 8; ++j) acc[j] = W[j] + wreg[0];
        }
        float4* pp = (float4*)(part + wave * 512 + lane * 8);
        pp[0] = make_float4(acc[0], acc[1], acc[2], acc[3]);
        pp[1] = make_float4(acc[4], acc[5], acc[6], acc[7]);
    }
    __syncthreads();
    if (t < 512) {
        float r = bwp[wdst * 576 + 32 + t];
        #pragma unroll
        for (int p2 = 0; p2 < 9; ++p2) r = fminf(r, part[p2 * 512 + t]);
        bwp[wdst * 576 + 32 + t] = r;
    }
    __syncthreads();
}

// ---------------------------------------------------------------------------
// K_comb: 15 serial combines over Cb (in place). dir=+1 down, -1 up. 32 WGs.
// ---------------------------------------------------------------------------
__global__ __launch_bounds__(1024) void k_comb(float* __restrict__ Cb, int dir)
{
    __shared__ __align__(16) float bwp[16 * 576];
    __shared__ __align__(16) float part[9 * 512];
    __shared__ float wgt[72];
    int m = blockIdx.x, t = threadIdx.x, wave = t >> 6, lane = t & 63, c0 = lane << 3;
    float* Cm = Cb + m * 8192;

    bwp[wave * 576 + ((lane < 32) ? lane : lane + 512)] = BIGF;
    *(float4*)(bwp + wave * 576 + 32 + c0)     = *(const float4*)(Cm + wave * 512 + c0);
    *(float4*)(bwp + wave * 576 + 32 + c0 + 4) = *(const float4*)(Cm + wave * 512 + c0 + 4);
    if (t < 65) { int d = t - 32; int ad = d < 0 ? -d : d; wgt[t] = ad * SQ2 + (float)(32 - ad); }
    __syncthreads();
    float wreg[8];
    #pragma unroll
    for (int dt = 0; dt < 8; ++dt) wreg[dt] = BIGF;
    if (wave < 8) {
        #pragma unroll
        for (int dt = 0; dt < 8; ++dt) wreg[dt] = wgt[wave * 8 + dt];
    } else if (wave == 8) wreg[0] = wgt[64];

    #pragma unroll 1
    for (int i = 0; i < 15; ++i) {
        int w2 = (dir > 0) ? (1 + i) : (14 - i);
        combine(bwp, part, w2, w2 - dir, t, wave, lane, wreg);
    }
    *(float4*)(Cm + wave * 512 + c0)     = *(const float4*)(bwp + wave * 576 + 32 + c0);
    *(float4*)(Cm + wave * 512 + c0 + 4) = *(const float4*)(bwp + wave * 576 + 32 + c0 + 4);
}

// ---------------------------------------------------------------------------
// K_p3d1u: phase-3 down (seeded exact recurrence, write Y) + fused phase-1 up
// from the 62KB LDS stash. 512 WGs x 64. Ring deepened 8->16.
// ---------------------------------------------------------------------------
__global__ __launch_bounds__(64) void k_p3d1u(const float* __restrict__ X0,
                                              float* __restrict__ Y0,
                                              const float* __restrict__ Cb,
                                              float* __restrict__ Db)
{
    __shared__ __align__(16) float stash[31 * 512];   // rows 0..30 only (row31 in regs)
    int bi = blockIdx.x, m = bi >> 4, w = bi & 15;
    const float* X = X0 + ((long)m << 18);
    float* Y = Y0 + ((long)m << 18);
    const int L = threadIdx.x;
    int c0 = L << 3, a = w << 5;
    float p[8], buf[16][8];

    if (w == 0) {
        load_row8(X, 0, c0, p);
        store_row8(Y, 0, c0, p);
        *(float4*)(stash + 0 * 512 + L * 4)       = make_float4(p[0], p[1], p[2], p[3]);
        *(float4*)(stash + 0 * 512 + 256 + L * 4) = make_float4(p[4], p[5], p[6], p[7]);
        #pragma unroll
        for (int k = 1; k <= 15; ++k) load_row8(X, k, c0, buf[k & 15]);
        #pragma unroll
        for (int i = 1; i < 32; ++i) {
            if (i + 15 < 32) load_row8(X, i + 15, c0, buf[(i + 15) & 15]);
            float nv[8]; step8(buf[i & 15], p, nv);
            store_row8(Y, i, c0, nv);
            if (i < 31) {
                *(float4*)(stash + i * 512 + L * 4)       = make_float4(nv[0], nv[1], nv[2], nv[3]);
                *(float4*)(stash + i * 512 + 256 + L * 4) = make_float4(nv[4], nv[5], nv[6], nv[7]);
            }
            #pragma unroll
            for (int j = 0; j < 8; ++j) p[j] = nv[j];
        }
    } else {
        const float4* s = (const float4*)(Cb + m * 8192 + (w - 1) * 512 + c0);
        float4 s0 = s[0], s1 = s[1];
        p[0]=s0.x; p[1]=s0.y; p[2]=s0.z; p[3]=s0.w;
        p[4]=s1.x; p[5]=s1.y; p[6]=s1.z; p[7]=s1.w;
        #pragma unroll
        for (int k = 0; k < 15; ++k) load_row8(X, a + k, c0, buf[k & 15]);
        #pragma unroll
        for (int i = 0; i < 32; ++i) {
            if (i + 15 < 32) load_row8(X, a + i + 15, c0, buf[(i + 15) & 15]);
            float nv[8]; step8(buf[i & 15], p, nv);
            store_row8(Y, a + i, c0, nv);
            if (i < 31) {
                *(float4*)(stash + i * 512 + L * 4)       = make_float4(nv[0], nv[1], nv[2], nv[3]);
                *(float4*)(stash + i * 512 + 256 + L * 4) = make_float4(nv[4], nv[5], nv[6], nv[7]);
            }
            #pragma unroll
            for (int j = 0; j < 8; ++j) p[j] = nv[j];
        }
    }

    // fused phase-1 up from LDS stash; seed = row a+31 (in p)
    float q[8], cur[8];
    #pragma unroll
    for (int j = 0; j < 8; ++j) q[j] = p[j];
    {
        float4 x0 = *(const float4*)(stash + 30 * 512 + L * 4);
        float4 x1 = *(const float4*)(stash + 30 * 512 + 256 + L * 4);
        cur[0]=x0.x; cur[1]=x0.y; cur[2]=x0.z; cur[3]=x0.w;
        cur[4]=x1.x; cur[5]=x1.y; cur[6]=x1.z; cur[7]=x1.w;
    }
    #pragma unroll
    for (int i = 1; i < 32; ++i) {
        float nxt[8];
        if (i < 31) {
            float4 x0 = *(const float4*)(stash + (30 - i) * 512 + L * 4);
            float4 x1 = *(const float4*)(stash + (30 - i) * 512 + 256 + L * 4);
            nxt[0]=x0.x; nxt[1]=x0.y; nxt[2]=x0.z; nxt[3]=x0.w;
            nxt[4]=x1.x; nxt[5]=x1.y; nxt[6]=x1.z; nxt[7]=x1.w;
        }
        float nv[8]; step8(cur, q, nv);
        #pragma unroll
        for (int j = 0; j < 8; ++j) q[j] = nv[j];
        if (i < 31) {
            #pragma unroll
            for (int j = 0; j < 8; ++j) cur[j] = nxt[j];
        }
    }
    float4* o = (float4*)(Db + m * 8192 + w * 512 + c0);
    o[0] = make_float4(q[0], q[1], q[2], q[3]);
    o[1] = make_float4(q[4], q[5], q[6], q[7]);
}

// ---------------------------------------------------------------------------
// K_p3u: phase-3 up + fused TRANSPOSED write + minmax. Ring deepened 8->16.
// ---------------------------------------------------------------------------
__device__ __forceinline__ void tile_store(float* tile, int h, int c0, const float v[8])
{
    float4* q = (float4*)(tile + h * 516 + c0);
    q[0] = make_float4(v[0], v[1], v[2], v[3]);
    q[1] = make_float4(v[4], v[5], v[6], v[7]);
}
__device__ __forceinline__ void half_out(const float* tile, float* __restrict__ Xo,
                                         int a2, int L)
{
    int g = L >> 2, j = (L & 3) << 2;
    #pragma unroll
    for (int it = 0; it < 32; ++it) {
        int c = (it << 4) + g;
        float4 v = make_float4(tile[(j + 0) * 516 + c], tile[(j + 1) * 516 + c],
                               tile[(j + 2) * 516 + c], tile[(j + 3) * 516 + c]);
        *(float4*)(Xo + (long)c * 512 + a2 + j) = v;
    }
}

__global__ __launch_bounds__(64) void k_p3u(const float* __restrict__ Y0,
                                            float* __restrict__ Xo0,
                                            const float* __restrict__ Db,
                                            float* __restrict__ minmax,
                                            int final_pass)
{
    __shared__ __align__(16) float tile[16 * 516];
    int bi = blockIdx.x, m = bi >> 4, w = bi & 15;
    const float* Y = Y0 + ((long)m << 18);
    float* Xo = Xo0 + ((long)m << 18);
    int L = threadIdx.x, c0 = L << 3, a = w << 5;
    float p[8], buf[16][8];
    float mn = BIGF, mx = -BIGF;

    if (w == 15) {
        load_row8(Y, 511, c0, p);
        tile_store(tile, 15, c0, p);
        #pragma unroll
        for (int j = 0; j < 8; ++j) { mn = fminf(mn, p[j]); mx = fmaxf(mx, p[j]); }
        #pragma unroll
        for (int k = 1; k <= 15; ++k) load_row8(Y, 511 - k, c0, buf[k & 15]);
        #pragma unroll
        for (int i = 1; i < 16; ++i) {
            load_row8(Y, 511 - (i + 15), c0, buf[(i + 15) & 15]);
            float nv[8]; step8(buf[i & 15], p, nv);
            tile_store(tile, 15 - i, c0, nv);
            #pragma unroll
            for (int j = 0; j < 8; ++j) { p[j] = nv[j]; mn = fminf(mn, nv[j]); mx = fmaxf(mx, nv[j]); }
        }
        half_out(tile, Xo, a + 16, L);
        #pragma unroll
        for (int i = 16; i < 32; ++i) {
            if (i + 15 < 32) load_row8(Y, 511 - (i + 15), c0, buf[(i + 15) & 15]);
            float nv[8]; step8(buf[i & 15], p, nv);
            tile_store(tile, 31 - i, c0, nv);
            #pragma unroll
            for (int j = 0; j < 8; ++j) { p[j] = nv[j]; mn = fminf(mn, nv[j]); mx = fmaxf(mx, nv[j]); }
        }
        half_out(tile, Xo, a, L);
    } else {
        const float4* s = (const float4*)(Db + m * 8192 + (w + 1) * 512 + c0);
        float4 s0 = s[0], s1 = s[1];
        p[0]=s0.x; p[1]=s0.y; p[2]=s0.z; p[3]=s0.w;
        p[4]=s1.x; p[5]=s1.y; p[6]=s1.z; p[7]=s1.w;
        #pragma unroll
        for (int k = 0; k < 15; ++k) load_row8(Y, a + 31 - k, c0, buf[k & 15]);
        #pragma unroll
        for (int i = 0; i < 16; ++i) {
            load_row8(Y, a + 31 - (i + 15), c0, buf[(i + 15) & 15]);
            float nv[8]; step8(buf[i & 15], p, nv);
            tile_store(tile, 15 - i, c0, nv);
            #pragma unroll
            for (int j = 0; j < 8; ++j) { p[j] = nv[j]; mn = fminf(mn, nv[j]); mx = fmaxf(mx, nv[j]); }
        }
        half_out(tile, Xo, a + 16, L);
        #pragma unroll
        for (int i = 16; i < 32; ++i) {
            if (i + 15 < 32) load_row8(Y, a + 31 - (i + 15), c0, buf[(i + 15) & 15]);
            float nv[8]; step8(buf[i & 15], p, nv);
            tile_store(tile, 31 - i, c0, nv);
            #pragma unroll
            for (int j = 0; j < 8; ++j) { p[j] = nv[j]; mn = fminf(mn, nv[j]); mx = fmaxf(mx, nv[j]); }
        }
        half_out(tile, Xo, a, L);
    }

    if (final_pass) {
        for (int o = 32; o > 0; o >>= 1) {
            mn = fminf(mn, __shfl_down(mn, o));
            mx = fmaxf(mx, __shfl_down(mx, o));
        }
        if (L == 0) {
            atomicMin((int*)(minmax + 2 * m),     __float_as_int(mn));
            atomicMax((int*)(minmax + 2 * m + 1), __float_as_int(mx));
        }
    }
}

// ---------------------------------------------------------------------------
// K_loss: NORMALIZED bitonic sort (all comparators min-low) with med3 trick.
// lstage LDS slots XOR-half-swizzled (verified: conflicts 2.36M -> 786K).
// ---------------------------------------------------------------------------
__device__ __forceinline__ void cex(float& lo, float& hi)
{
    float l = fminf(lo, hi);
    hi = fmaxf(lo, hi);
    lo = l;
}
__device__ __forceinline__ void merge8asc(float v[8])
{
    cex(v[0],v[4]); cex(v[1],v[5]); cex(v[2],v[6]); cex(v[3],v[7]);
    cex(v[0],v[2]); cex(v[1],v[3]); cex(v[4],v[6]); cex(v[5],v[7]);
    cex(v[0],v[1]); cex(v[2],v[3]); cex(v[4],v[5]); cex(v[6],v[7]);
}
__device__ __forceinline__ void sort8asc(float v[8])
{
    cex(v[0],v[1]); cex(v[2],v[3]); cex(v[4],v[5]); cex(v[6],v[7]);   // k=2
    cex(v[0],v[3]); cex(v[1],v[2]); cex(v[4],v[7]); cex(v[5],v[6]);   // k=4 rev
    cex(v[0],v[1]); cex(v[2],v[3]); cex(v[4],v[5]); cex(v[6],v[7]);   // k=4 j=1
    cex(v[0],v[7]); cex(v[1],v[6]); cex(v[2],v[5]); cex(v[3],v[4]);   // k=8 rev
    cex(v[0],v[2]); cex(v[1],v[3]); cex(v[4],v[6]); cex(v[5],v[7]);   // j=2
    cex(v[0],v[1]); cex(v[2],v[3]); cex(v[4],v[5]); cex(v[6],v[7]);   // j=1
}
__device__ __forceinline__ void xshfl(float v[8], int j8, float sel)
{
    #pragma unroll
    for (int e = 0; e < 8; ++e) {
        float o = __shfl_xor(v[e], j8);
        v[e] = fmed3(v[e], o, sel);
    }
}
template<int CTRL>
__device__ __forceinline__ void xdpp(float v[8], float sel)
{
    #pragma unroll
    for (int e = 0; e < 8; ++e) {
        float o = qdpp<CTRL>(v[e]);
        v[e] = fmed3(v[e], o, sel);
    }
}
__device__ __forceinline__ void rshfl(float v[8], int tmask, float sel)
{
    float o[8];
    #pragma unroll
    for (int e = 0; e < 8; ++e) o[e] = __shfl_xor(v[7 - e], tmask);
    #pragma unroll
    for (int e = 0; e < 8; ++e) v[e] = fmed3(v[e], o[e], sel);
}
template<int CTRL>
__device__ __forceinline__ void rdpp(float v[8], float sel)
{
    float o[8];
    #pragma unroll
    for (int e = 0; e < 8; ++e) o[e] = qdpp<CTRL>(v[7 - e]);
    #pragma unroll
    for (int e = 0; e < 8; ++e) v[e] = fmed3(v[e], o[e], sel);
}
__device__ __forceinline__ void lstage(float p[8], float q[8], int tmask, float sel, bool rev,
                                       float* sp, float* st, int t)
{
    __syncthreads();
    int sw = (t >> 2) & 1;                 // half-swap swizzle bit
    int o0 = t * 8 + sw * 4;
    int o1 = t * 8 + (sw ^ 1) * 4;
    *(float4*)(sp + o0) = make_float4(p[0], p[1], p[2], p[3]);
    *(float4*)(sp + o1) = make_float4(p[4], p[5], p[6], p[7]);
    *(float4*)(st + o0) = make_float4(q[0], q[1], q[2], q[3]);
    *(float4*)(st + o1) = make_float4(q[4], q[5], q[6], q[7]);
    __syncthreads();
    int pt = t ^ tmask;
    int psw = (pt >> 2) & 1;
    int q0 = pt * 8 + psw * 4;
    int q1 = pt * 8 + (psw ^ 1) * 4;
    float4 a = *(const float4*)(sp + q0), bb = *(const float4*)(sp + q1);
    float4 c = *(const float4*)(st + q0), d = *(const float4*)(st + q1);
    float op[8] = {a.x,a.y,a.z,a.w,bb.x,bb.y,bb.z,bb.w};
    float oq[8] = {c.x,c.y,c.z,c.w,d.x,d.y,d.z,d.w};
    if (rev) {
        #pragma unroll
        for (int e = 0; e < 8; ++e) {
            p[e] = fmed3(p[e], op[7 - e], sel);
            q[e] = fmed3(q[e], oq[7 - e], sel);
        }
    } else {
        #pragma unroll
        for (int e = 0; e < 8; ++e) {
            p[e] = fmed3(p[e], op[e], sel);
            q[e] = fmed3(q[e], oq[e], sel);
        }
    }
}

__global__ __launch_bounds__(512) void k_loss(const float* __restrict__ bufB,
                                              const float* __restrict__ minmax,
                                              float* __restrict__ acc,
                                              unsigned* __restrict__ count,
                                              float* __restrict__ out)
{
    __shared__ float sp[4096];
    __shared__ float st[4096];
    __shared__ float rs[8];

    int t = threadIdx.x;
    int r = blockIdx.x & 7;
    int k = blockIdx.x >> 3;
    int b = r + 8 * (k >> 6);
    int w = k & 63;
    int wi = w >> 3, wj = w & 7;

    int i0 = t << 3;
    int y = wi * 64 + (i0 >> 6);
    int x = wj * 64 + (i0 & 63);

    float mnP = minmax[2 * b],        mxP = minmax[2 * b + 1];
    float mnT = minmax[2 * (16 + b)], mxT = minmax[2 * (16 + b) + 1];
    float sclP = 1.0f / (mxP - mnP + 1e-6f);
    float sclT = 1.0f / (mxT - mnT + 1e-6f);

    float p[8], q[8];
    {
        const float4* P4 = (const float4*)(bufB + (long)b * 262144 + y * 512 + x);
        const float4* T4 = (const float4*)(bufB + (long)(16 + b) * 262144 + y * 512 + x);
        float4 a = P4[0], bb = P4[1], c = T4[0], d = T4[1];
        p[0]=a.x; p[1]=a.y; p[2]=a.z; p[3]=a.w; p[4]=bb.x; p[5]=bb.y; p[6]=bb.z; p[7]=bb.w;
        q[0]=c.x; q[1]=c.y; q[2]=c.z; q[3]=c.w; q[4]=d.x;  q[5]=d.y;  q[6]=d.z;  q[7]=d.w;
        #pragma unroll
        for (int e = 0; e < 8; ++e) {
            p[e] = (p[e] - mnP) * sclP;
            q[e] = (q[e] - mnT) * sclT;
        }
    }

    const float INFP = __builtin_inff();
    sort8asc(p); sort8asc(q);

    #pragma unroll 1
    for (int kk = 16; kk <= 4096; kk <<= 1) {
        int tmask = (kk - 1) >> 3;
        float sel = ((t & (kk >> 4)) == 0) ? -INFP : INFP;
        if (kk == 16)        { rdpp<0xB1>(p, sel); rdpp<0xB1>(q, sel); }
        else if (kk == 32)   { rdpp<0x1B>(p, sel); rdpp<0x1B>(q, sel); }
        else if (tmask < 64) { rshfl(p, tmask, sel); rshfl(q, tmask, sel); }
        else                 lstage(p, q, tmask, sel, true, sp, st, t);

        #pragma unroll 1
        for (int j = kk >> 2; j >= 8; j >>= 1) {
            int j8 = j >> 3;
            float s2 = ((t & j8) == 0) ? -INFP : INFP;
            if (j8 == 1)      { xdpp<0xB1>(p, s2); xdpp<0xB1>(q, s2); }
            else if (j8 == 2) { xdpp<0x4E>(p, s2); xdpp<0x4E>(q, s2); }
            else if (j8 < 64) { xshfl(p, j8, s2); xshfl(q, j8, s2); }
            else              lstage(p, q, j8, s2, false, sp, st, t);
        }
        merge8asc(p); merge8asc(q);
    }

    float s = 0.0f;
    #pragma unroll
    for (int e = 0; e < 8; ++e) { float d = p[e] - q[e]; s += d * d; }
    for (int o = 32; o > 0; o >>= 1) s += __shfl_down(s, o);
    if ((t & 63) == 0) rs[t >> 6] = s;
    __syncthreads();
    if (t == 0) {
        float tot = 0.0f;
        #pragma unroll
        for (int i = 0; i < 8; ++i) tot += rs[i];
        atomicAdd(acc, tot);
        __threadfence();
        unsigned done = atomicAdd(count, 1u);
        if (done == 1023u) {
            float total = atomicAdd(acc, 0.0f);
            float mean = total * (1.0f / 4194304.0f);
            out[0] = mean * 0.005f;
            out[1] = mean;
        }
    }
}

extern "C" void kernel_launch(void* const* d_in, const int* in_sizes, int n_in,
                              void* d_out, int out_size, void* d_ws, size_t ws_size,
                              hipStream_t stream)
{
    const float* pred = (const float*)d_in[0];
    const float* tgt  = (const float*)d_in[1];
    float* out = (float*)d_out;

    char* ws = (char*)d_ws;
    float* bufA     = (float*)ws;                       // 32 MB
    float* bufB     = (float*)(ws + (32ull << 20));     // 32 MB (Y intermediate)
    float* Cb       = (float*)(ws + (64ull << 20));     // 1 MB boundary rows (down)
    float* Db       = (float*)(ws + (65ull << 20));     // 1 MB boundary rows (up)
    float* minmax   = (float*)(ws + (66ull << 20));     // 64 floats
    float* acc      = minmax + 64;
    unsigned* count = (unsigned*)(acc + 1);

    k_init<<<16 * 1024, 256, 0, stream>>>(pred, tgt, bufA, acc, count, minmax);

    for (int s = 0; s < 4; ++s) {
        k_p1d  <<<512,   64, 0, stream>>>(bufA, Cb);
        k_comb <<< 32, 1024, 0, stream>>>(Cb, +1);
        k_p3d1u<<<512,   64, 0, stream>>>(bufA, bufB, Cb, Db);
        k_comb <<< 32, 1024, 0, stream>>>(Db, -1);
        k_p3u  <<<512,   64, 0, stream>>>(bufB, bufA, Db, minmax, s == 3 ? 1 : 0);
    }

    k_loss<<<1024, 512, 0, stream>>>(bufA, minmax, acc, count, out);
}

// Round 10
// 392.238 us; speedup vs baseline: 2.9303x; 1.0935x over previous
//
#include <hip/hip_runtime.h>

#define BIGF 1e20f
#define VF   1e10f

constexpr float SQ2 = 1.41421356237309515f;  // fp32 0x3FB504F3, == jnp.sqrt(2.0) in f32

// ---------------------------------------------------------------------------
// DPP helpers
// ---------------------------------------------------------------------------
__device__ __forceinline__ float dpp_left(float x)
{
    int o = __builtin_amdgcn_update_dpp(0x60AD78ECu /*1e20f*/, __float_as_int(x),
                                        0x138, 0xF, 0xF, false);   // WAVE_SHR1
    return __int_as_float(o);
}
__device__ __forceinline__ float dpp_right(float x)
{
    int o = __builtin_amdgcn_update_dpp(0x60AD78ECu /*1e20f*/, __float_as_int(x),
                                        0x130, 0xF, 0xF, false);   // WAVE_SHL1
    return __int_as_float(o);
}
template<int CTRL>
__device__ __forceinline__ float qdpp(float x)   // quad_perm xor patterns
{
    return __int_as_float(__builtin_amdgcn_update_dpp(0, __float_as_int(x),
                                                      CTRL, 0xF, 0xF, true));
}
__device__ __forceinline__ float fmed3(float a, float b, float c)
{
    return __builtin_amdgcn_fmed3f(a, b, c);
}

__device__ __forceinline__ void load_row8(const float* __restrict__ M, int r, int c0, float v[8])
{
    const float4* q = (const float4*)(M + ((long)r << 9) + c0);
    float4 a = q[0], b = q[1];
    v[0] = a.x; v[1] = a.y; v[2] = a.z; v[3] = a.w;
    v[4] = b.x; v[5] = b.y; v[6] = b.z; v[7] = b.w;
}
__device__ __forceinline__ void store_row8(float* __restrict__ M, int r, int c0, const float v[8])
{
    float4* q = (float4*)(M + ((long)r << 9) + c0);
    q[0] = make_float4(v[0], v[1], v[2], v[3]);
    q[1] = make_float4(v[4], v[5], v[6], v[7]);
}

// 3pt chamfer step: nv <- min(cur, p+1, min(neighbors)+SQ2)
__device__ __forceinline__ void step8(const float cur[8], const float p[8], float nv[8])
{
    float left  = dpp_left(p[7]);
    float right = dpp_right(p[0]);
    #pragma unroll
    for (int j = 0; j < 8; ++j) {
        float l  = (j == 0) ? left  : p[j - 1];
        float rr = (j == 7) ? right : p[j + 1];
        nv[j] = fminf(fminf(cur[j], p[j] + 1.0f), fminf(l, rr) + SQ2);
    }
}

// ---------------------------------------------------------------------------
// K1: binarize + channel max + dist init + scalar inits. VECTORIZED float4
// (4 px/thread, 4096 blocks): 6x b128 loads + 2x b128 stores replaces 8
// scalar-dword streams. Per-pixel arithmetic identical.
// ---------------------------------------------------------------------------
__global__ __launch_bounds__(256) void k_init(const float* __restrict__ pred,
                                              const float* __restrict__ tgt,
                                              float* __restrict__ bufA,
                                              float* __restrict__ acc,
                                              unsigned* __restrict__ count,
                                              float* __restrict__ minmax)
{
    if (blockIdx.x == 0 && threadIdx.x == 0) { *acc = 0.0f; *count = 0u; }
    if (blockIdx.x == 0 && threadIdx.x < 64)
        minmax[threadIdx.x] = (threadIdx.x & 1) ? 0.0f : BIGF;

    int r = blockIdx.x & 7;
    int k = blockIdx.x >> 3;                       // 0..511
    int b = r + 8 * (k >> 8);                      // 0..15
    int pix = ((k & 255) * 256 + threadIdx.x) << 2;
    long base = (long)b * 3 * 262144 + pix;

    float4 p0 = *(const float4*)(pred + base);
    float4 p1 = *(const float4*)(pred + base + 262144);
    float4 p2 = *(const float4*)(pred + base + 2 * 262144);
    float4 t0 = *(const float4*)(tgt + base);
    float4 t1 = *(const float4*)(tgt + base + 262144);
    float4 t2 = *(const float4*)(tgt + base + 2 * 262144);

    float P0[4] = {p0.x, p0.y, p0.z, p0.w};
    float P1[4] = {p1.x, p1.y, p1.z, p1.w};
    float P2[4] = {p2.x, p2.y, p2.z, p2.w};
    float T0[4] = {t0.x, t0.y, t0.z, t0.w};
    float T1[4] = {t1.x, t1.y, t1.z, t1.w};
    float T2[4] = {t2.x, t2.y, t2.z, t2.w};

    float oP[4], oT[4];
    #pragma unroll
    for (int e = 0; e < 4; ++e) {
        bool fgP = ((P0[e] + 1.0f) * 0.5f >= 0.7f) ||
                   ((P1[e] + 1.0f) * 0.5f >= 0.7f) ||
                   ((P2[e] + 1.0f) * 0.5f >= 0.7f);
        float mt = fmaxf(fmaxf(T0[e], T1[e]), T2[e]);
        oP[e] = fgP ? 0.0f : VF;
        oT[e] = VF * (1.0f - mt);
    }
    *(float4*)(bufA + (long)b * 262144 + pix)        = make_float4(oP[0], oP[1], oP[2], oP[3]);
    *(float4*)(bufA + (long)(16 + b) * 262144 + pix) = make_float4(oT[0], oT[1], oT[2], oT[3]);
}

// ---------------------------------------------------------------------------
// K_p1d: phase-1 down. 512 WGs (m = bi>>4, block w = bi&15), 64 threads.
// 8-deep ring (7 rows in flight) — R1-verified optimum.
// ---------------------------------------------------------------------------
__global__ __launch_bounds__(64) void k_p1d(const float* __restrict__ X0,
                                            float* __restrict__ Cb)
{
    int bi = blockIdx.x, m = bi >> 4, w = bi & 15;
    const float* X = X0 + ((long)m << 18);
    int c0 = (int)threadIdx.x << 3, a = w << 5;
    float p[8]; load_row8(X, a, c0, p);
    float buf[8][8];
    #pragma unroll
    for (int k = 1; k <= 7; ++k) load_row8(X, a + k, c0, buf[k & 7]);
    #pragma unroll
    for (int i = 1; i < 32; ++i) {
        if (i + 7 < 32) load_row8(X, a + i + 7, c0, buf[(i + 7) & 7]);
        float nv[8]; step8(buf[i & 7], p, nv);
        #pragma unroll
        for (int j = 0; j < 8; ++j) p[j] = nv[j];
    }
    float4* o = (float4*)(Cb + m * 8192 + w * 512 + c0);
    o[0] = make_float4(p[0], p[1], p[2], p[3]);
    o[1] = make_float4(p[4], p[5], p[6], p[7]);
}

// ---------------------------------------------------------------------------
// combine: bwp[wdst] = min(bwp[wdst], cone32(bwp[wsrc]))  (verified exact)
// ---------------------------------------------------------------------------
__device__ __forceinline__ void combine(float* __restrict__ bwp, float* __restrict__ part,
                                        int wdst, int wsrc, int t, int wave, int lane,
                                        const float wreg[8])
{
    const float* bs = bwp + wsrc * 576;
    if (wave <= 8) {
        int base = lane * 8 + 8 * wave;
        float W[16];
        float4 W0 = *(const float4*)(bs + base);
        float4 W1 = *(const float4*)(bs + base + 4);
        W[0]=W0.x; W[1]=W0.y; W[2]=W0.z; W[3]=W0.w;
        W[4]=W1.x; W[5]=W1.y; W[6]=W1.z; W[7]=W1.w;
        float acc[8];
        if (wave < 8) {
            float4 W2 = *(const float4*)(bs + base + 8);
            float4 W3 = *(const float4*)(bs + base + 12);
            W[8]=W2.x; W[9]=W2.y; W[10]=W2.z; W[11]=W2.w;
            W[12]=W3.x; W[13]=W3.y; W[14]=W3.z; W[15]=W3.w;
            #pragma unroll
            for (int j = 0; j < 8; ++j) acc[j] = W[j] + wreg[0];
            #pragma unroll
            for (int dt = 1; dt < 8; ++dt)
                #pragma unroll
                for (int j = 0; j < 8; ++j)
                    acc[j] = fminf(acc[j], W[j + dt] + wreg[dt]);
        } else {
            #pragma unroll
            for (int j = 0; j < 8; ++j) acc[j] = W[j] + wreg[0];
        }
        float4* pp = (float4*)(part + wave * 512 + lane * 8);
        pp[0] = make_float4(acc[0], acc[1], acc[2], acc[3]);
        pp[1] = make_float4(acc[4], acc[5], acc[6], acc[7]);
    }
    __syncthreads();
    if (t < 512) {
        float r = bwp[wdst * 576 + 32 + t];
        #pragma unroll
        for (int p2 = 0; p2 < 9; ++p2) r = fminf(r, part[p2 * 512 + t]);
        bwp[wdst * 576 + 32 + t] = r;
    }
    __syncthreads();
}

// ---------------------------------------------------------------------------
// K_comb: 15 serial combines over Cb (in place). dir=+1 down, -1 up. 32 WGs.
// ---------------------------------------------------------------------------
__global__ __launch_bounds__(1024) void k_comb(float* __restrict__ Cb, int dir)
{
    __shared__ __align__(16) float bwp[16 * 576];
    __shared__ __align__(16) float part[9 * 512];
    __shared__ float wgt[72];
    int m = blockIdx.x, t = threadIdx.x, wave = t >> 6, lane = t & 63, c0 = lane << 3;
    float* Cm = Cb + m * 8192;

    bwp[wave * 576 + ((lane < 32) ? lane : lane + 512)] = BIGF;
    *(float4*)(bwp + wave * 576 + 32 + c0)     = *(const float4*)(Cm + wave * 512 + c0);
    *(float4*)(bwp + wave * 576 + 32 + c0 + 4) = *(const float4*)(Cm + wave * 512 + c0 + 4);
    if (t < 65) { int d = t - 32; int ad = d < 0 ? -d : d; wgt[t] = ad * SQ2 + (float)(32 - ad); }
    __syncthreads();
    float wreg[8];
    #pragma unroll
    for (int dt = 0; dt < 8; ++dt) wreg[dt] = BIGF;
    if (wave < 8) {
        #pragma unroll
        for (int dt = 0; dt < 8; ++dt) wreg[dt] = wgt[wave * 8 + dt];
    } else if (wave == 8) wreg[0] = wgt[64];

    #pragma unroll 1
    for (int i = 0; i < 15; ++i) {
        int w2 = (dir > 0) ? (1 + i) : (14 - i);
        combine(bwp, part, w2, w2 - dir, t, wave, lane, wreg);
    }
    *(float4*)(Cm + wave * 512 + c0)     = *(const float4*)(bwp + wave * 576 + 32 + c0);
    *(float4*)(Cm + wave * 512 + c0 + 4) = *(const float4*)(bwp + wave * 576 + 32 + c0 + 4);
}

// ---------------------------------------------------------------------------
// K_p3d1u: phase-3 down (seeded exact recurrence, write Y) + fused phase-1 up
// reading its own rows from a 62KB LDS stash. 512 WGs x 64. 8-deep ring.
// ---------------------------------------------------------------------------
__global__ __launch_bounds__(64) void k_p3d1u(const float* __restrict__ X0,
                                              float* __restrict__ Y0,
                                              const float* __restrict__ Cb,
                                              float* __restrict__ Db)
{
    __shared__ __align__(16) float stash[31 * 512];   // rows 0..30 only (row31 in regs)
    int bi = blockIdx.x, m = bi >> 4, w = bi & 15;
    const float* X = X0 + ((long)m << 18);
    float* Y = Y0 + ((long)m << 18);
    const int L = threadIdx.x;
    int c0 = L << 3, a = w << 5;
    float p[8], buf[8][8];

    if (w == 0) {
        load_row8(X, 0, c0, p);
        store_row8(Y, 0, c0, p);
        *(float4*)(stash + 0 * 512 + L * 4)       = make_float4(p[0], p[1], p[2], p[3]);
        *(float4*)(stash + 0 * 512 + 256 + L * 4) = make_float4(p[4], p[5], p[6], p[7]);
        #pragma unroll
        for (int k = 1; k <= 7; ++k) load_row8(X, k, c0, buf[k & 7]);
        #pragma unroll
        for (int i = 1; i < 32; ++i) {
            if (i + 7 < 32) load_row8(X, i + 7, c0, buf[(i + 7) & 7]);
            float nv[8]; step8(buf[i & 7], p, nv);
            store_row8(Y, i, c0, nv);
            if (i < 31) {
                *(float4*)(stash + i * 512 + L * 4)       = make_float4(nv[0], nv[1], nv[2], nv[3]);
                *(float4*)(stash + i * 512 + 256 + L * 4) = make_float4(nv[4], nv[5], nv[6], nv[7]);
            }
            #pragma unroll
            for (int j = 0; j < 8; ++j) p[j] = nv[j];
        }
    } else {
        const float4* s = (const float4*)(Cb + m * 8192 + (w - 1) * 512 + c0);
        float4 s0 = s[0], s1 = s[1];
        p[0]=s0.x; p[1]=s0.y; p[2]=s0.z; p[3]=s0.w;
        p[4]=s1.x; p[5]=s1.y; p[6]=s1.z; p[7]=s1.w;
        #pragma unroll
        for (int k = 0; k < 7; ++k) load_row8(X, a + k, c0, buf[k & 7]);
        #pragma unroll
        for (int i = 0; i < 32; ++i) {
            if (i + 7 < 32) load_row8(X, a + i + 7, c0, buf[(i + 7) & 7]);
            float nv[8]; step8(buf[i & 7], p, nv);
            store_row8(Y, a + i, c0, nv);
            if (i < 31) {
                *(float4*)(stash + i * 512 + L * 4)       = make_float4(nv[0], nv[1], nv[2], nv[3]);
                *(float4*)(stash + i * 512 + 256 + L * 4) = make_float4(nv[4], nv[5], nv[6], nv[7]);
            }
            #pragma unroll
            for (int j = 0; j < 8; ++j) p[j] = nv[j];
        }
    }

    // fused phase-1 up from LDS stash; seed = row a+31 (in p)
    float q[8], cur[8];
    #pragma unroll
    for (int j = 0; j < 8; ++j) q[j] = p[j];
    {
        float4 x0 = *(const float4*)(stash + 30 * 512 + L * 4);
        float4 x1 = *(const float4*)(stash + 30 * 512 + 256 + L * 4);
        cur[0]=x0.x; cur[1]=x0.y; cur[2]=x0.z; cur[3]=x0.w;
        cur[4]=x1.x; cur[5]=x1.y; cur[6]=x1.z; cur[7]=x1.w;
    }
    #pragma unroll
    for (int i = 1; i < 32; ++i) {
        float nxt[8];
        if (i < 31) {
            float4 x0 = *(const float4*)(stash + (30 - i) * 512 + L * 4);
            float4 x1 = *(const float4*)(stash + (30 - i) * 512 + 256 + L * 4);
            nxt[0]=x0.x; nxt[1]=x0.y; nxt[2]=x0.z; nxt[3]=x0.w;
            nxt[4]=x1.x; nxt[5]=x1.y; nxt[6]=x1.z; nxt[7]=x1.w;
        }
        float nv[8]; step8(cur, q, nv);
        #pragma unroll
        for (int j = 0; j < 8; ++j) q[j] = nv[j];
        if (i < 31) {
            #pragma unroll
            for (int j = 0; j < 8; ++j) cur[j] = nxt[j];
        }
    }
    float4* o = (float4*)(Db + m * 8192 + w * 512 + c0);
    o[0] = make_float4(q[0], q[1], q[2], q[3]);
    o[1] = make_float4(q[4], q[5], q[6], q[7]);
}

// ---------------------------------------------------------------------------
// K_p3u: phase-3 up + fused TRANSPOSED write + minmax. 8-deep ring.
// ---------------------------------------------------------------------------
__device__ __forceinline__ void tile_store(float* tile, int h, int c0, const float v[8])
{
    float4* q = (float4*)(tile + h * 516 + c0);
    q[0] = make_float4(v[0], v[1], v[2], v[3]);
    q[1] = make_float4(v[4], v[5], v[6], v[7]);
}
__device__ __forceinline__ void half_out(const float* tile, float* __restrict__ Xo,
                                         int a2, int L)
{
    int g = L >> 2, j = (L & 3) << 2;
    #pragma unroll
    for (int it = 0; it < 32; ++it) {
        int c = (it << 4) + g;
        float4 v = make_float4(tile[(j + 0) * 516 + c], tile[(j + 1) * 516 + c],
                               tile[(j + 2) * 516 + c], tile[(j + 3) * 516 + c]);
        *(float4*)(Xo + (long)c * 512 + a2 + j) = v;
    }
}

__global__ __launch_bounds__(64) void k_p3u(const float* __restrict__ Y0,
                                            float* __restrict__ Xo0,
                                            const float* __restrict__ Db,
                                            float* __restrict__ minmax,
                                            int final_pass)
{
    __shared__ __align__(16) float tile[16 * 516];
    int bi = blockIdx.x, m = bi >> 4, w = bi & 15;
    const float* Y = Y0 + ((long)m << 18);
    float* Xo = Xo0 + ((long)m << 18);
    int L = threadIdx.x, c0 = L << 3, a = w << 5;
    float p[8], buf[8][8];
    float mn = BIGF, mx = -BIGF;

    if (w == 15) {
        load_row8(Y, 511, c0, p);
        tile_store(tile, 15, c0, p);
        #pragma unroll
        for (int j = 0; j < 8; ++j) { mn = fminf(mn, p[j]); mx = fmaxf(mx, p[j]); }
        #pragma unroll
        for (int k = 1; k <= 3; ++k) load_row8(Y, 511 - k, c0, buf[k & 3]);
        #pragma unroll
        for (int i = 1; i < 16; ++i) {
            load_row8(Y, 511 - (i + 3), c0, buf[(i + 3) & 3]);
            float nv[8]; step8(buf[i & 3], p, nv);
            tile_store(tile, 15 - i, c0, nv);
            #pragma unroll
            for (int j = 0; j < 8; ++j) { p[j] = nv[j]; mn = fminf(mn, nv[j]); mx = fmaxf(mx, nv[j]); }
        }
        half_out(tile, Xo, a + 16, L);
        #pragma unroll
        for (int i = 16; i < 32; ++i) {
            if (i + 3 < 32) load_row8(Y, 511 - (i + 3), c0, buf[(i + 3) & 3]);
            float nv[8]; step8(buf[i & 3], p, nv);
            tile_store(tile, 31 - i, c0, nv);
            #pragma unroll
            for (int j = 0; j < 8; ++j) { p[j] = nv[j]; mn = fminf(mn, nv[j]); mx = fmaxf(mx, nv[j]); }
        }
        half_out(tile, Xo, a, L);
    } else {
        const float4* s = (const float4*)(Db + m * 8192 + (w + 1) * 512 + c0);
        float4 s0 = s[0], s1 = s[1];
        p[0]=s0.x; p[1]=s0.y; p[2]=s0.z; p[3]=s0.w;
        p[4]=s1.x; p[5]=s1.y; p[6]=s1.z; p[7]=s1.w;
        #pragma unroll
        for (int k = 0; k < 3; ++k) load_row8(Y, a + 31 - k, c0, buf[k & 3]);
        #pragma unroll
        for (int i = 0; i < 16; ++i) {
            load_row8(Y, a + 31 - (i + 3), c0, buf[(i + 3) & 3]);
            float nv[8]; step8(buf[i & 3], p, nv);
            tile_store(tile, 15 - i, c0, nv);
            #pragma unroll
            for (int j = 0; j < 8; ++j) { p[j] = nv[j]; mn = fminf(mn, nv[j]); mx = fmaxf(mx, nv[j]); }
        }
        half_out(tile, Xo, a + 16, L);
        #pragma unroll
        for (int i = 16; i < 32; ++i) {
            if (i + 3 < 32) load_row8(Y, a + 31 - (i + 3), c0, buf[(i + 3) & 3]);
            float nv[8]; step8(buf[i & 3], p, nv);
            tile_store(tile, 31 - i, c0, nv);
            #pragma unroll
            for (int j = 0; j < 8; ++j) { p[j] = nv[j]; mn = fminf(mn, nv[j]); mx = fmaxf(mx, nv[j]); }
        }
        half_out(tile, Xo, a, L);
    }

    if (final_pass) {
        for (int o = 32; o > 0; o >>= 1) {
            mn = fminf(mn, __shfl_down(mn, o));
            mx = fmaxf(mx, __shfl_down(mx, o));
        }
        if (L == 0) {
            atomicMin((int*)(minmax + 2 * m),     __float_as_int(mn));
            atomicMax((int*)(minmax + 2 * m + 1), __float_as_int(mx));
        }
    }
}

// ---------------------------------------------------------------------------
// K_loss: NORMALIZED bitonic sort (all comparators min-low) with med3 trick.
// lstage LDS slots XOR-half-swizzled (verified: conflicts 2.36M -> 786K).
// ---------------------------------------------------------------------------
__device__ __forceinline__ void cex(float& lo, float& hi)
{
    float l = fminf(lo, hi);
    hi = fmaxf(lo, hi);
    lo = l;
}
__device__ __forceinline__ void merge8asc(float v[8])
{
    cex(v[0],v[4]); cex(v[1],v[5]); cex(v[2],v[6]); cex(v[3],v[7]);
    cex(v[0],v[2]); cex(v[1],v[3]); cex(v[4],v[6]); cex(v[5],v[7]);
    cex(v[0],v[1]); cex(v[2],v[3]); cex(v[4],v[5]); cex(v[6],v[7]);
}
__device__ __forceinline__ void sort8asc(float v[8])
{
    cex(v[0],v[1]); cex(v[2],v[3]); cex(v[4],v[5]); cex(v[6],v[7]);   // k=2
    cex(v[0],v[3]); cex(v[1],v[2]); cex(v[4],v[7]); cex(v[5],v[6]);   // k=4 rev
    cex(v[0],v[1]); cex(v[2],v[3]); cex(v[4],v[5]); cex(v[6],v[7]);   // k=4 j=1
    cex(v[0],v[7]); cex(v[1],v[6]); cex(v[2],v[5]); cex(v[3],v[4]);   // k=8 rev
    cex(v[0],v[2]); cex(v[1],v[3]); cex(v[4],v[6]); cex(v[5],v[7]);   // j=2
    cex(v[0],v[1]); cex(v[2],v[3]); cex(v[4],v[5]); cex(v[6],v[7]);   // j=1
}
__device__ __forceinline__ void xshfl(float v[8], int j8, float sel)
{
    #pragma unroll
    for (int e = 0; e < 8; ++e) {
        float o = __shfl_xor(v[e], j8);
        v[e] = fmed3(v[e], o, sel);
    }
}
template<int CTRL>
__device__ __forceinline__ void xdpp(float v[8], float sel)
{
    #pragma unroll
    for (int e = 0; e < 8; ++e) {
        float o = qdpp<CTRL>(v[e]);
        v[e] = fmed3(v[e], o, sel);
    }
}
__device__ __forceinline__ void rshfl(float v[8], int tmask, float sel)
{
    float o[8];
    #pragma unroll
    for (int e = 0; e < 8; ++e) o[e] = __shfl_xor(v[7 - e], tmask);
    #pragma unroll
    for (int e = 0; e < 8; ++e) v[e] = fmed3(v[e], o[e], sel);
}
template<int CTRL>
__device__ __forceinline__ void rdpp(float v[8], float sel)
{
    float o[8];
    #pragma unroll
    for (int e = 0; e < 8; ++e) o[e] = qdpp<CTRL>(v[7 - e]);
    #pragma unroll
    for (int e = 0; e < 8; ++e) v[e] = fmed3(v[e], o[e], sel);
}
__device__ __forceinline__ void lstage(float p[8], float q[8], int tmask, float sel, bool rev,
                                       float* sp, float* st, int t)
{
    __syncthreads();
    int sw = (t >> 2) & 1;                 // half-swap swizzle bit
    int o0 = t * 8 + sw * 4;
    int o1 = t * 8 + (sw ^ 1) * 4;
    *(float4*)(sp + o0) = make_float4(p[0], p[1], p[2], p[3]);
    *(float4*)(sp + o1) = make_float4(p[4], p[5], p[6], p[7]);
    *(float4*)(st + o0) = make_float4(q[0], q[1], q[2], q[3]);
    *(float4*)(st + o1) = make_float4(q[4], q[5], q[6], q[7]);
    __syncthreads();
    int pt = t ^ tmask;
    int psw = (pt >> 2) & 1;
    int q0 = pt * 8 + psw * 4;
    int q1 = pt * 8 + (psw ^ 1) * 4;
    float4 a = *(const float4*)(sp + q0), bb = *(const float4*)(sp + q1);
    float4 c = *(const float4*)(st + q0), d = *(const float4*)(st + q1);
    float op[8] = {a.x,a.y,a.z,a.w,bb.x,bb.y,bb.z,bb.w};
    float oq[8] = {c.x,c.y,c.z,c.w,d.x,d.y,d.z,d.w};
    if (rev) {
        #pragma unroll
        for (int e = 0; e < 8; ++e) {
            p[e] = fmed3(p[e], op[7 - e], sel);
            q[e] = fmed3(q[e], oq[7 - e], sel);
        }
    } else {
        #pragma unroll
        for (int e = 0; e < 8; ++e) {
            p[e] = fmed3(p[e], op[e], sel);
            q[e] = fmed3(q[e], oq[e], sel);
        }
    }
}

__global__ __launch_bounds__(512) void k_loss(const float* __restrict__ bufB,
                                              const float* __restrict__ minmax,
                                              float* __restrict__ acc,
                                              unsigned* __restrict__ count,
                                              float* __restrict__ out)
{
    __shared__ float sp[4096];
    __shared__ float st[4096];
    __shared__ float rs[8];

    int t = threadIdx.x;
    int r = blockIdx.x & 7;
    int k = blockIdx.x >> 3;
    int b = r + 8 * (k >> 6);
    int w = k & 63;
    int wi = w >> 3, wj = w & 7;

    int i0 = t << 3;
    int y = wi * 64 + (i0 >> 6);
    int x = wj * 64 + (i0 & 63);

    float mnP = minmax[2 * b],        mxP = minmax[2 * b + 1];
    float mnT = minmax[2 * (16 + b)], mxT = minmax[2 * (16 + b) + 1];
    float sclP = 1.0f / (mxP - mnP + 1e-6f);
    float sclT = 1.0f / (mxT - mnT + 1e-6f);

    float p[8], q[8];
    {
        const float4* P4 = (const float4*)(bufB + (long)b * 262144 + y * 512 + x);
        const float4* T4 = (const float4*)(bufB + (long)(16 + b) * 262144 + y * 512 + x);
        float4 a = P4[0], bb = P4[1], c = T4[0], d = T4[1];
        p[0]=a.x; p[1]=a.y; p[2]=a.z; p[3]=a.w; p[4]=bb.x; p[5]=bb.y; p[6]=bb.z; p[7]=bb.w;
        q[0]=c.x; q[1]=c.y; q[2]=c.z; q[3]=c.w; q[4]=d.x;  q[5]=d.y;  q[6]=d.z;  q[7]=d.w;
        #pragma unroll
        for (int e = 0; e < 8; ++e) {
            p[e] = (p[e] - mnP) * sclP;
            q[e] = (q[e] - mnT) * sclT;
        }
    }

    const float INFP = __builtin_inff();
    sort8asc(p); sort8asc(q);

    #pragma unroll 1
    for (int kk = 16; kk <= 4096; kk <<= 1) {
        int tmask = (kk - 1) >> 3;
        float sel = ((t & (kk >> 4)) == 0) ? -INFP : INFP;
        if (kk == 16)        { rdpp<0xB1>(p, sel); rdpp<0xB1>(q, sel); }
        else if (kk == 32)   { rdpp<0x1B>(p, sel); rdpp<0x1B>(q, sel); }
        else if (tmask < 64) { rshfl(p, tmask, sel); rshfl(q, tmask, sel); }
        else                 lstage(p, q, tmask, sel, true, sp, st, t);

        #pragma unroll 1
        for (int j = kk >> 2; j >= 8; j >>= 1) {
            int j8 = j >> 3;
            float s2 = ((t & j8) == 0) ? -INFP : INFP;
            if (j8 == 1)      { xdpp<0xB1>(p, s2); xdpp<0xB1>(q, s2); }
            else if (j8 == 2) { xdpp<0x4E>(p, s2); xdpp<0x4E>(q, s2); }
            else if (j8 < 64) { xshfl(p, j8, s2); xshfl(q, j8, s2); }
            else              lstage(p, q, j8, s2, false, sp, st, t);
        }
        merge8asc(p); merge8asc(q);
    }

    float s = 0.0f;
    #pragma unroll
    for (int e = 0; e < 8; ++e) { float d = p[e] - q[e]; s += d * d; }
    for (int o = 32; o > 0; o >>= 1) s += __shfl_down(s, o);
    if ((t & 63) == 0) rs[t >> 6] = s;
    __syncthreads();
    if (t == 0) {
        float tot = 0.0f;
        #pragma unroll
        for (int i = 0; i < 8; ++i) tot += rs[i];
        atomicAdd(acc, tot);
        __threadfence();
        unsigned done = atomicAdd(count, 1u);
        if (done == 1023u) {
            float total = atomicAdd(acc, 0.0f);
            float mean = total * (1.0f / 4194304.0f);
            out[0] = mean * 0.005f;
            out[1] = mean;
        }
    }
}

extern "C" void kernel_launch(void* const* d_in, const int* in_sizes, int n_in,
                              void* d_out, int out_size, void* d_ws, size_t ws_size,
                              hipStream_t stream)
{
    const float* pred = (const float*)d_in[0];
    const float* tgt  = (const float*)d_in[1];
    float* out = (float*)d_out;

    char* ws = (char*)d_ws;
    float* bufA     = (float*)ws;                       // 32 MB
    float* bufB     = (float*)(ws + (32ull << 20));     // 32 MB (Y intermediate)
    float* Cb       = (float*)(ws + (64ull << 20));     // 1 MB boundary rows (down)
    float* Db       = (float*)(ws + (65ull << 20));     // 1 MB boundary rows (up)
    float* minmax   = (float*)(ws + (66ull << 20));     // 64 floats
    float* acc      = minmax + 64;
    unsigned* count = (unsigned*)(acc + 1);

    k_init<<<4096, 256, 0, stream>>>(pred, tgt, bufA, acc, count, minmax);

    for (int s = 0; s < 4; ++s) {
        k_p1d  <<<512,   64, 0, stream>>>(bufA, Cb);
        k_comb <<< 32, 1024, 0, stream>>>(Cb, +1);
        k_p3d1u<<<512,   64, 0, stream>>>(bufA, bufB, Cb, Db);
        k_comb <<< 32, 1024, 0, stream>>>(Db, -1);
        k_p3u  <<<512,   64, 0, stream>>>(bufB, bufA, Db, minmax, s == 3 ? 1 : 0);
    }

    k_loss<<<1024, 512, 0, stream>>>(bufA, minmax, acc, count, out);
}

// Round 11
// 385.695 us; speedup vs baseline: 2.9800x; 1.0170x over previous
//
#include <hip/hip_runtime.h>

#define BIGF 1e20f
#define VF   1e10f

constexpr float SQ2 = 1.41421356237309515f;  // fp32 0x3FB504F3, == jnp.sqrt(2.0) in f32

// ---------------------------------------------------------------------------
// DPP helpers
// ---------------------------------------------------------------------------
__device__ __forceinline__ float dpp_left(float x)
{
    int o = __builtin_amdgcn_update_dpp(0x60AD78ECu /*1e20f*/, __float_as_int(x),
                                        0x138, 0xF, 0xF, false);   // WAVE_SHR1
    return __int_as_float(o);
}
__device__ __forceinline__ float dpp_right(float x)
{
    int o = __builtin_amdgcn_update_dpp(0x60AD78ECu /*1e20f*/, __float_as_int(x),
                                        0x130, 0xF, 0xF, false);   // WAVE_SHL1
    return __int_as_float(o);
}
template<int CTRL>
__device__ __forceinline__ float qdpp(float x)   // quad_perm xor patterns
{
    return __int_as_float(__builtin_amdgcn_update_dpp(0, __float_as_int(x),
                                                      CTRL, 0xF, 0xF, true));
}
__device__ __forceinline__ float fmed3(float a, float b, float c)
{
    return __builtin_amdgcn_fmed3f(a, b, c);
}

__device__ __forceinline__ void load_row8(const float* __restrict__ M, int r, int c0, float v[8])
{
    const float4* q = (const float4*)(M + ((long)r << 9) + c0);
    float4 a = q[0], b = q[1];
    v[0] = a.x; v[1] = a.y; v[2] = a.z; v[3] = a.w;
    v[4] = b.x; v[5] = b.y; v[6] = b.z; v[7] = b.w;
}

// 3pt chamfer step: nv <- min(cur, p+1, min(neighbors)+SQ2)
__device__ __forceinline__ void step8(const float cur[8], const float p[8], float nv[8])
{
    float left  = dpp_left(p[7]);
    float right = dpp_right(p[0]);
    #pragma unroll
    for (int j = 0; j < 8; ++j) {
        float l  = (j == 0) ? left  : p[j - 1];
        float rr = (j == 7) ? right : p[j + 1];
        nv[j] = fminf(fminf(cur[j], p[j] + 1.0f), fminf(l, rr) + SQ2);
    }
}

// ---------------------------------------------------------------------------
// K1: binarize + channel max + dist init + scalar inits. Vectorized float4
// (verified R10 win: issue-limited before, -14us).
// ---------------------------------------------------------------------------
__global__ __launch_bounds__(256) void k_init(const float* __restrict__ pred,
                                              const float* __restrict__ tgt,
                                              float* __restrict__ bufA,
                                              float* __restrict__ acc,
                                              unsigned* __restrict__ count,
                                              float* __restrict__ minmax)
{
    if (blockIdx.x == 0 && threadIdx.x == 0) { *acc = 0.0f; *count = 0u; }
    if (blockIdx.x == 0 && threadIdx.x < 64)
        minmax[threadIdx.x] = (threadIdx.x & 1) ? 0.0f : BIGF;

    int r = blockIdx.x & 7;
    int k = blockIdx.x >> 3;                       // 0..511
    int b = r + 8 * (k >> 8);                      // 0..15
    int pix = ((k & 255) * 256 + threadIdx.x) << 2;
    long base = (long)b * 3 * 262144 + pix;

    float4 p0 = *(const float4*)(pred + base);
    float4 p1 = *(const float4*)(pred + base + 262144);
    float4 p2 = *(const float4*)(pred + base + 2 * 262144);
    float4 t0 = *(const float4*)(tgt + base);
    float4 t1 = *(const float4*)(tgt + base + 262144);
    float4 t2 = *(const float4*)(tgt + base + 2 * 262144);

    float P0[4] = {p0.x, p0.y, p0.z, p0.w};
    float P1[4] = {p1.x, p1.y, p1.z, p1.w};
    float P2[4] = {p2.x, p2.y, p2.z, p2.w};
    float T0[4] = {t0.x, t0.y, t0.z, t0.w};
    float T1[4] = {t1.x, t1.y, t1.z, t1.w};
    float T2[4] = {t2.x, t2.y, t2.z, t2.w};

    float oP[4], oT[4];
    #pragma unroll
    for (int e = 0; e < 4; ++e) {
        bool fgP = ((P0[e] + 1.0f) * 0.5f >= 0.7f) ||
                   ((P1[e] + 1.0f) * 0.5f >= 0.7f) ||
                   ((P2[e] + 1.0f) * 0.5f >= 0.7f);
        float mt = fmaxf(fmaxf(T0[e], T1[e]), T2[e]);
        oP[e] = fgP ? 0.0f : VF;
        oT[e] = VF * (1.0f - mt);
    }
    *(float4*)(bufA + (long)b * 262144 + pix)        = make_float4(oP[0], oP[1], oP[2], oP[3]);
    *(float4*)(bufA + (long)(16 + b) * 262144 + pix) = make_float4(oT[0], oT[1], oT[2], oT[3]);
}

// ---------------------------------------------------------------------------
// K_p1d: phase-1 down. 512 WGs x 64. 8-deep ring (R1-verified optimum).
// ---------------------------------------------------------------------------
__global__ __launch_bounds__(64) void k_p1d(const float* __restrict__ X0,
                                            float* __restrict__ Cb)
{
    int bi = blockIdx.x, m = bi >> 4, w = bi & 15;
    const float* X = X0 + ((long)m << 18);
    int c0 = (int)threadIdx.x << 3, a = w << 5;
    float p[8]; load_row8(X, a, c0, p);
    float buf[8][8];
    #pragma unroll
    for (int k = 1; k <= 7; ++k) load_row8(X, a + k, c0, buf[k & 7]);
    #pragma unroll
    for (int i = 1; i < 32; ++i) {
        if (i + 7 < 32) load_row8(X, a + i + 7, c0, buf[(i + 7) & 7]);
        float nv[8]; step8(buf[i & 7], p, nv);
        #pragma unroll
        for (int j = 0; j < 8; ++j) p[j] = nv[j];
    }
    float4* o = (float4*)(Cb + m * 8192 + w * 512 + c0);
    o[0] = make_float4(p[0], p[1], p[2], p[3]);
    o[1] = make_float4(p[4], p[5], p[6], p[7]);
}

// ---------------------------------------------------------------------------
// combine: bwp[wdst] = min(bwp[wdst], cone32(bwp[wsrc]))  (verified exact)
// ---------------------------------------------------------------------------
__device__ __forceinline__ void combine(float* __restrict__ bwp, float* __restrict__ part,
                                        int wdst, int wsrc, int t, int wave, int lane,
                                        const float wreg[8])
{
    const float* bs = bwp + wsrc * 576;
    if (wave <= 8) {
        int base = lane * 8 + 8 * wave;
        float W[16];
        float4 W0 = *(const float4*)(bs + base);
        float4 W1 = *(const float4*)(bs + base + 4);
        W[0]=W0.x; W[1]=W0.y; W[2]=W0.z; W[3]=W0.w;
        W[4]=W1.x; W[5]=W1.y; W[6]=W1.z; W[7]=W1.w;
        float acc[8];
        if (wave < 8) {
            float4 W2 = *(const float4*)(bs + base + 8);
            float4 W3 = *(const float4*)(bs + base + 12);
            W[8]=W2.x; W[9]=W2.y; W[10]=W2.z; W[11]=W2.w;
            W[12]=W3.x; W[13]=W3.y; W[14]=W3.z; W[15]=W3.w;
            #pragma unroll
            for (int j = 0; j < 8; ++j) acc[j] = W[j] + wreg[0];
            #pragma unroll
            for (int dt = 1; dt < 8; ++dt)
                #pragma unroll
                for (int j = 0; j < 8; ++j)
                    acc[j] = fminf(acc[j], W[j + dt] + wreg[dt]);
        } else {
            #pragma unroll
            for (int j = 0; j < 8; ++j) acc[j] = W[j] + wreg[0];
        }
        float4* pp = (float4*)(part + wave * 512 + lane * 8);
        pp[0] = make_float4(acc[0], acc[1], acc[2], acc[3]);
        pp[1] = make_float4(acc[4], acc[5], acc[6], acc[7]);
    }
    __syncthreads();
    if (t < 512) {
        float r = bwp[wdst * 576 + 32 + t];
        #pragma unroll
        for (int p2 = 0; p2 < 9; ++p2) r = fminf(r, part[p2 * 512 + t]);
        bwp[wdst * 576 + 32 + t] = r;
    }
    __syncthreads();
}

// ---------------------------------------------------------------------------
// K_comb: 15 serial combines over Cb (in place). dir=+1 down, -1 up. 32 WGs.
// ---------------------------------------------------------------------------
__global__ __launch_bounds__(1024) void k_comb(float* __restrict__ Cb, int dir)
{
    __shared__ __align__(16) float bwp[16 * 576];
    __shared__ __align__(16) float part[9 * 512];
    __shared__ float wgt[72];
    int m = blockIdx.x, t = threadIdx.x, wave = t >> 6, lane = t & 63, c0 = lane << 3;
    float* Cm = Cb + m * 8192;

    bwp[wave * 576 + ((lane < 32) ? lane : lane + 512)] = BIGF;
    *(float4*)(bwp + wave * 576 + 32 + c0)     = *(const float4*)(Cm + wave * 512 + c0);
    *(float4*)(bwp + wave * 576 + 32 + c0 + 4) = *(const float4*)(Cm + wave * 512 + c0 + 4);
    if (t < 65) { int d = t - 32; int ad = d < 0 ? -d : d; wgt[t] = ad * SQ2 + (float)(32 - ad); }
    __syncthreads();
    float wreg[8];
    #pragma unroll
    for (int dt = 0; dt < 8; ++dt) wreg[dt] = BIGF;
    if (wave < 8) {
        #pragma unroll
        for (int dt = 0; dt < 8; ++dt) wreg[dt] = wgt[wave * 8 + dt];
    } else if (wave == 8) wreg[0] = wgt[64];

    #pragma unroll 1
    for (int i = 0; i < 15; ++i) {
        int w2 = (dir > 0) ? (1 + i) : (14 - i);
        combine(bwp, part, w2, w2 - dir, t, wave, lane, wreg);
    }
    *(float4*)(Cm + wave * 512 + c0)     = *(const float4*)(bwp + wave * 576 + 32 + c0);
    *(float4*)(Cm + wave * 512 + c0 + 4) = *(const float4*)(bwp + wave * 576 + 32 + c0 + 4);
}

// ---------------------------------------------------------------------------
// K_pb: boundary producer (ex-p3d1u, Y writes ELIMINATED). Seeded down from
// X + scanned Cb (unified: w==0 seed = BIGF, bit-exact identity), stash down
// rows, fused band-local up1 -> Db boundary only (1MB). 512 WGs x 64.
// ---------------------------------------------------------------------------
__global__ __launch_bounds__(64) void k_pb(const float* __restrict__ X0,
                                           const float* __restrict__ Cb,
                                           float* __restrict__ Db)
{
    __shared__ __align__(16) float stash[31 * 512];   // down rows a+0..a+30 (row31 in regs)
    int bi = blockIdx.x, m = bi >> 4, w = bi & 15;
    const float* X = X0 + ((long)m << 18);
    const int L = threadIdx.x;
    int c0 = L << 3, a = w << 5;
    float p[8], buf[8][8];

    if (w) {
        const float4* s = (const float4*)(Cb + m * 8192 + (w - 1) * 512 + c0);
        float4 s0 = s[0], s1 = s[1];
        p[0]=s0.x; p[1]=s0.y; p[2]=s0.z; p[3]=s0.w;
        p[4]=s1.x; p[5]=s1.y; p[6]=s1.z; p[7]=s1.w;
    } else {
        #pragma unroll
        for (int j = 0; j < 8; ++j) p[j] = BIGF;
    }

    #pragma unroll
    for (int k = 0; k < 7; ++k) load_row8(X, a + k, c0, buf[k & 7]);
    #pragma unroll
    for (int i = 0; i < 32; ++i) {
        if (i + 7 < 32) load_row8(X, a + i + 7, c0, buf[(i + 7) & 7]);
        float nv[8]; step8(buf[i & 7], p, nv);
        if (i < 31) {
            *(float4*)(stash + i * 512 + L * 4)       = make_float4(nv[0], nv[1], nv[2], nv[3]);
            *(float4*)(stash + i * 512 + 256 + L * 4) = make_float4(nv[4], nv[5], nv[6], nv[7]);
        }
        #pragma unroll
        for (int j = 0; j < 8; ++j) p[j] = nv[j];
    }

    // fused band-local up1; seed = down row a+31 (in p)
    float q[8], cur[8];
    #pragma unroll
    for (int j = 0; j < 8; ++j) q[j] = p[j];
    {
        float4 x0 = *(const float4*)(stash + 30 * 512 + L * 4);
        float4 x1 = *(const float4*)(stash + 30 * 512 + 256 + L * 4);
        cur[0]=x0.x; cur[1]=x0.y; cur[2]=x0.z; cur[3]=x0.w;
        cur[4]=x1.x; cur[5]=x1.y; cur[6]=x1.z; cur[7]=x1.w;
    }
    #pragma unroll
    for (int i = 1; i < 32; ++i) {
        float nxt[8];
        if (i < 31) {
            float4 x0 = *(const float4*)(stash + (30 - i) * 512 + L * 4);
            float4 x1 = *(const float4*)(stash + (30 - i) * 512 + 256 + L * 4);
            nxt[0]=x0.x; nxt[1]=x0.y; nxt[2]=x0.z; nxt[3]=x0.w;
            nxt[4]=x1.x; nxt[5]=x1.y; nxt[6]=x1.z; nxt[7]=x1.w;
        }
        float nv[8]; step8(cur, q, nv);
        #pragma unroll
        for (int j = 0; j < 8; ++j) q[j] = nv[j];
        if (i < 31) {
            #pragma unroll
            for (int j = 0; j < 8; ++j) cur[j] = nxt[j];
        }
    }
    float4* o = (float4*)(Db + m * 8192 + w * 512 + c0);
    o[0] = make_float4(q[0], q[1], q[2], q[3]);
    o[1] = make_float4(q[4], q[5], q[6], q[7]);
}

// ---------------------------------------------------------------------------
// K_p3u: recompute seeded down from X + scanned Cb into a 32-row LDS stash
// (stride 516 like the old tile), then seeded up IN PLACE from scanned Db,
// transposed flush in two 16-row halves + minmax. 512 WGs x 64. Y eliminated.
// ---------------------------------------------------------------------------
__device__ __forceinline__ void sst516(float* st, int slot, int c0, const float v[8])
{
    float4* q = (float4*)(st + slot * 516 + c0);
    q[0] = make_float4(v[0], v[1], v[2], v[3]);
    q[1] = make_float4(v[4], v[5], v[6], v[7]);
}
__device__ __forceinline__ void sld516(const float* st, int slot, int c0, float v[8])
{
    const float4* q = (const float4*)(st + slot * 516 + c0);
    float4 a = q[0], b = q[1];
    v[0]=a.x; v[1]=a.y; v[2]=a.z; v[3]=a.w;
    v[4]=b.x; v[5]=b.y; v[6]=b.z; v[7]=b.w;
}
__device__ __forceinline__ void half_out32(const float* st, float* __restrict__ Xo,
                                           int slotbase, int a2, int L)
{
    int g = L >> 2, j = (L & 3) << 2;
    #pragma unroll
    for (int it = 0; it < 32; ++it) {
        int c = (it << 4) + g;
        float4 v = make_float4(st[(slotbase + j + 0) * 516 + c],
                               st[(slotbase + j + 1) * 516 + c],
                               st[(slotbase + j + 2) * 516 + c],
                               st[(slotbase + j + 3) * 516 + c]);
        *(float4*)(Xo + (long)c * 512 + a2 + j) = v;
    }
}

__global__ __launch_bounds__(64) void k_p3u(const float* __restrict__ X0,
                                            float* __restrict__ Xo0,
                                            const float* __restrict__ Cb,
                                            const float* __restrict__ Db,
                                            float* __restrict__ minmax,
                                            int final_pass)
{
    __shared__ __align__(16) float stash[32 * 516];   // 66048 B; 2 WGs/CU
    int bi = blockIdx.x, m = bi >> 4, w = bi & 15;
    const float* X = X0 + ((long)m << 18);
    float* Xo = Xo0 + ((long)m << 18);
    const int L = threadIdx.x;
    int c0 = L << 3, a = w << 5;
    float p[8], buf[8][8];

    // ---- seeded down recompute (identical math to k_pb's down) ----
    if (w) {
        const float4* s = (const float4*)(Cb + m * 8192 + (w - 1) * 512 + c0);
        float4 s0 = s[0], s1 = s[1];
        p[0]=s0.x; p[1]=s0.y; p[2]=s0.z; p[3]=s0.w;
        p[4]=s1.x; p[5]=s1.y; p[6]=s1.z; p[7]=s1.w;
    } else {
        #pragma unroll
        for (int j = 0; j < 8; ++j) p[j] = BIGF;
    }
    #pragma unroll
    for (int k = 0; k < 7; ++k) load_row8(X, a + k, c0, buf[k & 7]);
    #pragma unroll
    for (int i = 0; i < 32; ++i) {
        if (i + 7 < 32) load_row8(X, a + i + 7, c0, buf[(i + 7) & 7]);
        float nv[8]; step8(buf[i & 7], p, nv);
        sst516(stash, i, c0, nv);                      // down row a+i at slot i
        #pragma unroll
        for (int j = 0; j < 8; ++j) p[j] = nv[j];
    }

    // ---- seeded up in place + minmax ----
    float s2[8];
    if (w < 15) {
        const float4* s = (const float4*)(Db + m * 8192 + (w + 1) * 512 + c0);
        float4 s0 = s[0], s1 = s[1];
        s2[0]=s0.x; s2[1]=s0.y; s2[2]=s0.z; s2[3]=s0.w;
        s2[4]=s1.x; s2[5]=s1.y; s2[6]=s1.z; s2[7]=s1.w;
    } else {
        #pragma unroll
        for (int j = 0; j < 8; ++j) s2[j] = BIGF;      // step8 with BIG seed == identity
    }
    float mn = BIGF, mx = -BIGF;
    #pragma unroll
    for (int i = 0; i < 16; ++i) {                     // up rows a+31..a+16 at slots 31..16
        float cu[8];
        if (i == 0) {
            #pragma unroll
            for (int j = 0; j < 8; ++j) cu[j] = p[j];  // down row a+31 (regs, skip LDS)
        } else {
            sld516(stash, 31 - i, c0, cu);
        }
        float nv[8]; step8(cu, s2, nv);
        sst516(stash, 31 - i, c0, nv);
        #pragma unroll
        for (int j = 0; j < 8; ++j) { s2[j] = nv[j]; mn = fminf(mn, nv[j]); mx = fmaxf(mx, nv[j]); }
    }
    half_out32(stash, Xo, 16, a + 16, L);
    #pragma unroll
    for (int i = 16; i < 32; ++i) {                    // up rows a+15..a at slots 15..0
        float cu[8]; sld516(stash, 31 - i, c0, cu);
        float nv[8]; step8(cu, s2, nv);
        sst516(stash, 31 - i, c0, nv);
        #pragma unroll
        for (int j = 0; j < 8; ++j) { s2[j] = nv[j]; mn = fminf(mn, nv[j]); mx = fmaxf(mx, nv[j]); }
    }
    half_out32(stash, Xo, 0, a, L);

    if (final_pass) {
        for (int o = 32; o > 0; o >>= 1) {
            mn = fminf(mn, __shfl_down(mn, o));
            mx = fmaxf(mx, __shfl_down(mx, o));
        }
        if (L == 0) {
            atomicMin((int*)(minmax + 2 * m),     __float_as_int(mn));
            atomicMax((int*)(minmax + 2 * m + 1), __float_as_int(mx));
        }
    }
}

// ---------------------------------------------------------------------------
// K_loss: NORMALIZED bitonic sort (all comparators min-low) with med3 trick.
// lstage LDS slots XOR-half-swizzled (verified: conflicts 2.36M -> 786K).
// ---------------------------------------------------------------------------
__device__ __forceinline__ void cex(float& lo, float& hi)
{
    float l = fminf(lo, hi);
    hi = fmaxf(lo, hi);
    lo = l;
}
__device__ __forceinline__ void merge8asc(float v[8])
{
    cex(v[0],v[4]); cex(v[1],v[5]); cex(v[2],v[6]); cex(v[3],v[7]);
    cex(v[0],v[2]); cex(v[1],v[3]); cex(v[4],v[6]); cex(v[5],v[7]);
    cex(v[0],v[1]); cex(v[2],v[3]); cex(v[4],v[5]); cex(v[6],v[7]);
}
__device__ __forceinline__ void sort8asc(float v[8])
{
    cex(v[0],v[1]); cex(v[2],v[3]); cex(v[4],v[5]); cex(v[6],v[7]);   // k=2
    cex(v[0],v[3]); cex(v[1],v[2]); cex(v[4],v[7]); cex(v[5],v[6]);   // k=4 rev
    cex(v[0],v[1]); cex(v[2],v[3]); cex(v[4],v[5]); cex(v[6],v[7]);   // k=4 j=1
    cex(v[0],v[7]); cex(v[1],v[6]); cex(v[2],v[5]); cex(v[3],v[4]);   // k=8 rev
    cex(v[0],v[2]); cex(v[1],v[3]); cex(v[4],v[6]); cex(v[5],v[7]);   // j=2
    cex(v[0],v[1]); cex(v[2],v[3]); cex(v[4],v[5]); cex(v[6],v[7]);   // j=1
}
__device__ __forceinline__ void xshfl(float v[8], int j8, float sel)
{
    #pragma unroll
    for (int e = 0; e < 8; ++e) {
        float o = __shfl_xor(v[e], j8);
        v[e] = fmed3(v[e], o, sel);
    }
}
template<int CTRL>
__device__ __forceinline__ void xdpp(float v[8], float sel)
{
    #pragma unroll
    for (int e = 0; e < 8; ++e) {
        float o = qdpp<CTRL>(v[e]);
        v[e] = fmed3(v[e], o, sel);
    }
}
__device__ __forceinline__ void rshfl(float v[8], int tmask, float sel)
{
    float o[8];
    #pragma unroll
    for (int e = 0; e < 8; ++e) o[e] = __shfl_xor(v[7 - e], tmask);
    #pragma unroll
    for (int e = 0; e < 8; ++e) v[e] = fmed3(v[e], o[e], sel);
}
template<int CTRL>
__device__ __forceinline__ void rdpp(float v[8], float sel)
{
    float o[8];
    #pragma unroll
    for (int e = 0; e < 8; ++e) o[e] = qdpp<CTRL>(v[7 - e]);
    #pragma unroll
    for (int e = 0; e < 8; ++e) v[e] = fmed3(v[e], o[e], sel);
}
__device__ __forceinline__ void lstage(float p[8], float q[8], int tmask, float sel, bool rev,
                                       float* sp, float* st, int t)
{
    __syncthreads();
    int sw = (t >> 2) & 1;                 // half-swap swizzle bit
    int o0 = t * 8 + sw * 4;
    int o1 = t * 8 + (sw ^ 1) * 4;
    *(float4*)(sp + o0) = make_float4(p[0], p[1], p[2], p[3]);
    *(float4*)(sp + o1) = make_float4(p[4], p[5], p[6], p[7]);
    *(float4*)(st + o0) = make_float4(q[0], q[1], q[2], q[3]);
    *(float4*)(st + o1) = make_float4(q[4], q[5], q[6], q[7]);
    __syncthreads();
    int pt = t ^ tmask;
    int psw = (pt >> 2) & 1;
    int q0 = pt * 8 + psw * 4;
    int q1 = pt * 8 + (psw ^ 1) * 4;
    float4 a = *(const float4*)(sp + q0), bb = *(const float4*)(sp + q1);
    float4 c = *(const float4*)(st + q0), d = *(const float4*)(st + q1);
    float op[8] = {a.x,a.y,a.z,a.w,bb.x,bb.y,bb.z,bb.w};
    float oq[8] = {c.x,c.y,c.z,c.w,d.x,d.y,d.z,d.w};
    if (rev) {
        #pragma unroll
        for (int e = 0; e < 8; ++e) {
            p[e] = fmed3(p[e], op[7 - e], sel);
            q[e] = fmed3(q[e], oq[7 - e], sel);
        }
    } else {
        #pragma unroll
        for (int e = 0; e < 8; ++e) {
            p[e] = fmed3(p[e], op[e], sel);
            q[e] = fmed3(q[e], oq[e], sel);
        }
    }
}

__global__ __launch_bounds__(512) void k_loss(const float* __restrict__ bufB,
                                              const float* __restrict__ minmax,
                                              float* __restrict__ acc,
                                              unsigned* __restrict__ count,
                                              float* __restrict__ out)
{
    __shared__ float sp[4096];
    __shared__ float st[4096];
    __shared__ float rs[8];

    int t = threadIdx.x;
    int r = blockIdx.x & 7;
    int k = blockIdx.x >> 3;
    int b = r + 8 * (k >> 6);
    int w = k & 63;
    int wi = w >> 3, wj = w & 7;

    int i0 = t << 3;
    int y = wi * 64 + (i0 >> 6);
    int x = wj * 64 + (i0 & 63);

    float mnP = minmax[2 * b],        mxP = minmax[2 * b + 1];
    float mnT = minmax[2 * (16 + b)], mxT = minmax[2 * (16 + b) + 1];
    float sclP = 1.0f / (mxP - mnP + 1e-6f);
    float sclT = 1.0f / (mxT - mnT + 1e-6f);

    float p[8], q[8];
    {
        const float4* P4 = (const float4*)(bufB + (long)b * 262144 + y * 512 + x);
        const float4* T4 = (const float4*)(bufB + (long)(16 + b) * 262144 + y * 512 + x);
        float4 a = P4[0], bb = P4[1], c = T4[0], d = T4[1];
        p[0]=a.x; p[1]=a.y; p[2]=a.z; p[3]=a.w; p[4]=bb.x; p[5]=bb.y; p[6]=bb.z; p[7]=bb.w;
        q[0]=c.x; q[1]=c.y; q[2]=c.z; q[3]=c.w; q[4]=d.x;  q[5]=d.y;  q[6]=d.z;  q[7]=d.w;
        #pragma unroll
        for (int e = 0; e < 8; ++e) {
            p[e] = (p[e] - mnP) * sclP;
            q[e] = (q[e] - mnT) * sclT;
        }
    }

    const float INFP = __builtin_inff();
    sort8asc(p); sort8asc(q);

    #pragma unroll 1
    for (int kk = 16; kk <= 4096; kk <<= 1) {
        int tmask = (kk - 1) >> 3;
        float sel = ((t & (kk >> 4)) == 0) ? -INFP : INFP;
        if (kk == 16)        { rdpp<0xB1>(p, sel); rdpp<0xB1>(q, sel); }
        else if (kk == 32)   { rdpp<0x1B>(p, sel); rdpp<0x1B>(q, sel); }
        else if (tmask < 64) { rshfl(p, tmask, sel); rshfl(q, tmask, sel); }
        else                 lstage(p, q, tmask, sel, true, sp, st, t);

        #pragma unroll 1
        for (int j = kk >> 2; j >= 8; j >>= 1) {
            int j8 = j >> 3;
            float s2 = ((t & j8) == 0) ? -INFP : INFP;
            if (j8 == 1)      { xdpp<0xB1>(p, s2); xdpp<0xB1>(q, s2); }
            else if (j8 == 2) { xdpp<0x4E>(p, s2); xdpp<0x4E>(q, s2); }
            else if (j8 < 64) { xshfl(p, j8, s2); xshfl(q, j8, s2); }
            else              lstage(p, q, j8, s2, false, sp, st, t);
        }
        merge8asc(p); merge8asc(q);
    }

    float s = 0.0f;
    #pragma unroll
    for (int e = 0; e < 8; ++e) { float d = p[e] - q[e]; s += d * d; }
    for (int o = 32; o > 0; o >>= 1) s += __shfl_down(s, o);
    if ((t & 63) == 0) rs[t >> 6] = s;
    __syncthreads();
    if (t == 0) {
        float tot = 0.0f;
        #pragma unroll
        for (int i = 0; i < 8; ++i) tot += rs[i];
        atomicAdd(acc, tot);
        __threadfence();
        unsigned done = atomicAdd(count, 1u);
        if (done == 1023u) {
            float total = atomicAdd(acc, 0.0f);
            float mean = total * (1.0f / 4194304.0f);
            out[0] = mean * 0.005f;
            out[1] = mean;
        }
    }
}

extern "C" void kernel_launch(void* const* d_in, const int* in_sizes, int n_in,
                              void* d_out, int out_size, void* d_ws, size_t ws_size,
                              hipStream_t stream)
{
    const float* pred = (const float*)d_in[0];
    const float* tgt  = (const float*)d_in[1];
    float* out = (float*)d_out;

    char* ws = (char*)d_ws;
    float* bufA     = (float*)ws;                       // 32 MB
    float* bufB     = (float*)(ws + (32ull << 20));     // 32 MB (ping-pong)
    float* Cb       = (float*)(ws + (64ull << 20));     // 1 MB boundary rows (down)
    float* Db       = (float*)(ws + (65ull << 20));     // 1 MB boundary rows (up)
    float* minmax   = (float*)(ws + (66ull << 20));     // 64 floats
    float* acc      = minmax + 64;
    unsigned* count = (unsigned*)(acc + 1);

    k_init<<<4096, 256, 0, stream>>>(pred, tgt, bufA, acc, count, minmax);

    for (int s = 0; s < 4; ++s) {
        const float* in = (s & 1) ? bufB : bufA;
        float* outb     = (s & 1) ? bufA : bufB;
        k_p1d <<<512,   64, 0, stream>>>(in, Cb);
        k_comb<<< 32, 1024, 0, stream>>>(Cb, +1);
        k_pb  <<<512,   64, 0, stream>>>(in, Cb, Db);
        k_comb<<< 32, 1024, 0, stream>>>(Db, -1);
        k_p3u <<<512,   64, 0, stream>>>(in, outb, Cb, Db, minmax, s == 3 ? 1 : 0);
    }

    k_loss<<<1024, 512, 0, stream>>>(bufA, minmax, acc, count, out);
}